// Round 1
// baseline (14969.852 us; speedup 1.0000x reference)
//
#include <hip/hip_runtime.h>
#include <hip/hip_bf16.h>

// ---------------------------------------------------------------------------
// TernaryCIFAR10Net: 3x [conv3x3(ternary W) + bias + relu + maxpool2] + 2 FC
// x: [1024,3,32,32] fp32. Output: [1024,10] fp32.
// Round 0: correctness-first direct fp32 implementation.
// ---------------------------------------------------------------------------

#define WS_WT1   0
#define N_WT1    (64*3*3*3)            // 1728
#define WS_WT2   (WS_WT1 + N_WT1)
#define N_WT2    (128*64*3*3)          // 73728
#define WS_WT3   (WS_WT2 + N_WT2)
#define N_WT3    (256*128*3*3)         // 294912
#define WS_WTF1  (WS_WT3 + N_WT3)
#define N_WTF1   (256*4096)            // 1048576
#define WS_WTF2  (WS_WTF1 + N_WTF1)
#define N_WTF2   (10*256)              // 2560
#define WS_A1    (WS_WTF2 + N_WTF2)
#define N_A1     (1024*64*16*16)       // 16777216
#define WS_A2    (WS_A1 + N_A1)
#define N_A2     (1024*128*8*8)        // 8388608
#define WS_A3    (WS_A2 + N_A2)
#define N_A3     (1024*256*4*4)        // 4194304
#define WS_F1    (WS_A3 + N_A3)
#define N_F1     (1024*256)

// ---------------------------------------------------------------------------
// Ternarize: delta = 0.7*mean|w|; alpha = sum(|w|*mask)/max(count,1);
// wt = alpha*sign(w)*mask.  Single block, 3 phases. Double-precision sums so
// delta/alpha are exact (borderline |w|>delta flips vs ref would be fatal).
// ---------------------------------------------------------------------------
template <int BLK>
__global__ void ternarize_kernel(const float* __restrict__ w, int n,
                                 float* __restrict__ wt) {
    __shared__ double red_a[BLK / 64];
    __shared__ double red_b[BLK / 64];
    __shared__ float s_delta, s_alpha;
    const int tid = threadIdx.x;
    const int lane = tid & 63;
    const int wv = tid >> 6;

    // Phase 1: sum |w|
    double s = 0.0;
    for (int i = tid; i < n; i += BLK) s += (double)fabsf(w[i]);
    #pragma unroll
    for (int off = 32; off > 0; off >>= 1) s += __shfl_down(s, off, 64);
    if (lane == 0) red_a[wv] = s;
    __syncthreads();
    if (tid == 0) {
        double t = 0.0;
        for (int i = 0; i < BLK / 64; i++) t += red_a[i];
        s_delta = (float)(0.7 * t / (double)n);
    }
    __syncthreads();
    const float delta = s_delta;

    // Phase 2: masked sum + count
    double ms = 0.0, cnt = 0.0;
    for (int i = tid; i < n; i += BLK) {
        float a = fabsf(w[i]);
        if (a > delta) { ms += (double)a; cnt += 1.0; }
    }
    #pragma unroll
    for (int off = 32; off > 0; off >>= 1) {
        ms += __shfl_down(ms, off, 64);
        cnt += __shfl_down(cnt, off, 64);
    }
    __syncthreads();  // red_a reuse safe only after all read s_delta
    if (lane == 0) { red_a[wv] = ms; red_b[wv] = cnt; }
    __syncthreads();
    if (tid == 0) {
        double tm = 0.0, tc = 0.0;
        for (int i = 0; i < BLK / 64; i++) { tm += red_a[i]; tc += red_b[i]; }
        s_alpha = (float)(tm / (tc > 1.0 ? tc : 1.0));
    }
    __syncthreads();
    const float alpha = s_alpha;

    // Phase 3: write ternarized weights
    for (int i = tid; i < n; i += BLK) {
        float v = w[i];
        float a = fabsf(v);
        wt[i] = (a > delta) ? (v > 0.0f ? alpha : -alpha) : 0.0f;
    }
}

// ---------------------------------------------------------------------------
// Fused conv3x3(pad 1) + bias + relu + maxpool2.
// One thread computes one pooled output pixel (4 conv outputs -> max).
// Block handles a fixed output channel (blockIdx.y); its CI*9 weights in LDS.
// relu(max(a)+b) == maxpool(relu(a+b)) since relu monotone, bias uniform.
// ---------------------------------------------------------------------------
template <int CI, int HI>
__global__ void conv_pool_kernel(const float* __restrict__ x,
                                 const float* __restrict__ wt,
                                 const float* __restrict__ bias,
                                 float* __restrict__ y,
                                 int B, int CO) {
    constexpr int PO = HI / 2;
    const int co = blockIdx.y;
    __shared__ float sw[CI * 9];
    for (int i = threadIdx.x; i < CI * 9; i += blockDim.x)
        sw[i] = wt[co * CI * 9 + i];
    __syncthreads();
    const float bv = bias[co];

    const int total = B * PO * PO;
    for (int idx = blockIdx.x * blockDim.x + threadIdx.x; idx < total;
         idx += gridDim.x * blockDim.x) {
        const int pw = idx % PO;
        const int t = idx / PO;
        const int ph = t % PO;
        const int b = t / PO;
        const int h0 = 2 * ph, w0 = 2 * pw;

        float acc00 = 0.f, acc01 = 0.f, acc10 = 0.f, acc11 = 0.f;
        const float* xb = x + (long)b * CI * HI * HI;
        for (int ci = 0; ci < CI; ci++) {
            const float* xc = xb + ci * HI * HI;
            float p[4][4];
            #pragma unroll
            for (int r = 0; r < 4; r++) {
                const int h = h0 - 1 + r;
                const bool hin = (h >= 0) && (h < HI);
                #pragma unroll
                for (int c = 0; c < 4; c++) {
                    const int w = w0 - 1 + c;
                    p[r][c] = (hin && w >= 0 && w < HI) ? xc[h * HI + w] : 0.f;
                }
            }
            const float* wr = sw + ci * 9;
            #pragma unroll
            for (int kh = 0; kh < 3; kh++) {
                #pragma unroll
                for (int kw = 0; kw < 3; kw++) {
                    const float wvv = wr[kh * 3 + kw];
                    acc00 += wvv * p[kh][kw];
                    acc01 += wvv * p[kh][kw + 1];
                    acc10 += wvv * p[kh + 1][kw];
                    acc11 += wvv * p[kh + 1][kw + 1];
                }
            }
        }
        float m = fmaxf(fmaxf(acc00, acc01), fmaxf(acc10, acc11));
        m = fmaxf(m + bv, 0.f);
        y[(((long)b * CO + co) * PO + ph) * PO + pw] = m;
    }
}

// ---------------------------------------------------------------------------
// FC1: out[b,j] = relu(dot(a[b,0:4096], wt[j,0:4096]) + bias[j]); j in [0,256)
// One block per b; x-row staged in LDS (broadcast reads); float4 weight loads.
// ---------------------------------------------------------------------------
__global__ void fc1_kernel(const float* __restrict__ a,
                           const float* __restrict__ wt,
                           const float* __restrict__ bias,
                           float* __restrict__ out) {
    __shared__ float sx[4096];
    const int b = blockIdx.x;
    for (int i = threadIdx.x; i < 4096; i += 256)
        sx[i] = a[(long)b * 4096 + i];
    __syncthreads();
    const int j = threadIdx.x;
    const float4* wr = (const float4*)(wt + (long)j * 4096);
    const float4* xr = (const float4*)sx;
    float acc = 0.f;
    #pragma unroll 4
    for (int i = 0; i < 1024; i++) {
        float4 w4 = wr[i];
        float4 x4 = xr[i];
        acc += w4.x * x4.x + w4.y * x4.y + w4.z * x4.z + w4.w * x4.w;
    }
    out[(long)b * 256 + j] = fmaxf(acc + bias[j], 0.f);
}

// ---------------------------------------------------------------------------
// FC2: out[b,k] = dot(a[b,0:256], wt[k,0:256]) + bias[k]; k in [0,10)
// ---------------------------------------------------------------------------
__global__ void fc2_kernel(const float* __restrict__ a,
                           const float* __restrict__ wt,
                           const float* __restrict__ bias,
                           float* __restrict__ out, int B) {
    const int idx = blockIdx.x * blockDim.x + threadIdx.x;
    if (idx >= B * 10) return;
    const int k = idx % 10;
    const int b = idx / 10;
    const float* ar = a + (long)b * 256;
    const float* wr = wt + (long)k * 256;
    float acc = 0.f;
    #pragma unroll 4
    for (int i = 0; i < 256; i++) acc += ar[i] * wr[i];
    out[idx] = acc + bias[k];
}

extern "C" void kernel_launch(void* const* d_in, const int* in_sizes, int n_in,
                              void* d_out, int out_size, void* d_ws, size_t ws_size,
                              hipStream_t stream) {
    const float* x   = (const float*)d_in[0];
    const float* w1  = (const float*)d_in[1];
    const float* b1  = (const float*)d_in[2];
    const float* w2  = (const float*)d_in[3];
    const float* b2  = (const float*)d_in[4];
    const float* w3  = (const float*)d_in[5];
    const float* b3  = (const float*)d_in[6];
    const float* wf1 = (const float*)d_in[7];
    const float* bf1 = (const float*)d_in[8];
    const float* wf2 = (const float*)d_in[9];
    const float* bf2 = (const float*)d_in[10];
    float* out = (float*)d_out;
    float* ws = (float*)d_ws;

    const int B = 1024;

    float* wt1  = ws + WS_WT1;
    float* wt2  = ws + WS_WT2;
    float* wt3  = ws + WS_WT3;
    float* wtf1 = ws + WS_WTF1;
    float* wtf2 = ws + WS_WTF2;
    float* a1   = ws + WS_A1;
    float* a2   = ws + WS_A2;
    float* a3   = ws + WS_A3;
    float* f1   = ws + WS_F1;

    // Ternarize all weights (tiny; single-block each)
    hipLaunchKernelGGL((ternarize_kernel<1024>), dim3(1), dim3(1024), 0, stream, w1,  N_WT1,  wt1);
    hipLaunchKernelGGL((ternarize_kernel<1024>), dim3(1), dim3(1024), 0, stream, w2,  N_WT2,  wt2);
    hipLaunchKernelGGL((ternarize_kernel<1024>), dim3(1), dim3(1024), 0, stream, w3,  N_WT3,  wt3);
    hipLaunchKernelGGL((ternarize_kernel<1024>), dim3(1), dim3(1024), 0, stream, wf1, N_WTF1, wtf1);
    hipLaunchKernelGGL((ternarize_kernel<1024>), dim3(1), dim3(1024), 0, stream, wf2, N_WTF2, wtf2);

    // Conv stages (fused conv+bias+relu+pool)
    {
        const int total = B * 16 * 16;                      // pooled pixels
        dim3 grid((total + 255) / 256, 64);
        hipLaunchKernelGGL((conv_pool_kernel<3, 32>), grid, dim3(256), 0, stream,
                           x, wt1, b1, a1, B, 64);
    }
    {
        const int total = B * 8 * 8;
        dim3 grid((total + 255) / 256, 128);
        hipLaunchKernelGGL((conv_pool_kernel<64, 16>), grid, dim3(256), 0, stream,
                           a1, wt2, b2, a2, B, 128);
    }
    {
        const int total = B * 4 * 4;
        dim3 grid((total + 255) / 256, 256);
        hipLaunchKernelGGL((conv_pool_kernel<128, 8>), grid, dim3(256), 0, stream,
                           a2, wt3, b3, a3, B, 256);
    }

    // FC1 + relu
    hipLaunchKernelGGL(fc1_kernel, dim3(B), dim3(256), 0, stream, a3, wtf1, bf1, f1);

    // FC2
    hipLaunchKernelGGL(fc2_kernel, dim3((B * 10 + 255) / 256), dim3(256), 0, stream,
                       f1, wtf2, bf2, out, B);
}

// Round 2
// 1819.445 us; speedup vs baseline: 8.2277x; 8.2277x over previous
//
#include <hip/hip_runtime.h>
#include <hip/hip_bf16.h>

// ---------------------------------------------------------------------------
// TernaryCIFAR10Net: 3x [conv3x3(ternary W) + bias + relu + maxpool2] + 2 FC
// Round 1: restructure convs for ILP + locality.
//   - each thread: 1 pooled pixel x NCO=8 output channels (288 FMA / 16 loads)
//   - weights for the co-chunk staged in LDS, padded to 12 floats -> float4
//     broadcast reads (ds_read_b128, conflict-free)
//   - blocks pack BIMG images so blockDim = 256
//   - fc1: 2 images/block, x-rows in LDS (kills per-image weight re-read)
//   - ternarize: 3-kernel multi-block with double-precision device atomics
// ---------------------------------------------------------------------------

#define WS_WT1   0
#define N_WT1    (64*3*3*3)            // 1728
#define WS_WT2   (WS_WT1 + N_WT1)
#define N_WT2    (128*64*3*3)          // 73728
#define WS_WT3   (WS_WT2 + N_WT2)
#define N_WT3    (256*128*3*3)         // 294912
#define WS_WTF1  (WS_WT3 + N_WT3)
#define N_WTF1   (256*4096)            // 1048576
#define WS_WTF2  (WS_WTF1 + N_WTF1)
#define N_WTF2   (10*256)              // 2560
#define WS_A1    (WS_WTF2 + N_WTF2)
#define N_A1     (1024*64*16*16)       // 16777216
#define WS_A2    (WS_A1 + N_A1)
#define N_A2     (1024*128*8*8)        // 8388608
#define WS_A3    (WS_A2 + N_A2)
#define N_A3     (1024*256*4*4)        // 4194304
#define WS_F1    (WS_A3 + N_A3)
#define N_F1     (1024*256)
#define WS_SCR   (WS_F1 + N_F1)        // 5 weights x 4 doubles (as 40 floats)

// ---------------------------------------------------------------------------
// Ternarize, 3-phase multi-block. scr[w] = {sum|w|, masked_sum, count, pad}
// doubles; zeroed by hipMemsetAsync before launch. Stream order guarantees
// phase k sees phase k-1's atomics (kernel-boundary release/acquire).
// ---------------------------------------------------------------------------
__global__ void tern_sum_abs(const float* __restrict__ w, int n,
                             double* __restrict__ scr) {
    double s = 0.0;
    for (int i = blockIdx.x * blockDim.x + threadIdx.x; i < n;
         i += gridDim.x * blockDim.x)
        s += (double)fabsf(w[i]);
    #pragma unroll
    for (int off = 32; off > 0; off >>= 1) s += __shfl_down(s, off, 64);
    __shared__ double red[4];
    const int lane = threadIdx.x & 63, wv = threadIdx.x >> 6;
    if (lane == 0) red[wv] = s;
    __syncthreads();
    if (threadIdx.x == 0)
        atomicAdd(scr, red[0] + red[1] + red[2] + red[3]);
}

__global__ void tern_masked(const float* __restrict__ w, int n,
                            double* __restrict__ scr) {
    const float delta = (float)(0.7 * scr[0] / (double)n);
    double ms = 0.0, cnt = 0.0;
    for (int i = blockIdx.x * blockDim.x + threadIdx.x; i < n;
         i += gridDim.x * blockDim.x) {
        float a = fabsf(w[i]);
        if (a > delta) { ms += (double)a; cnt += 1.0; }
    }
    #pragma unroll
    for (int off = 32; off > 0; off >>= 1) {
        ms += __shfl_down(ms, off, 64);
        cnt += __shfl_down(cnt, off, 64);
    }
    __shared__ double redm[4], redc[4];
    const int lane = threadIdx.x & 63, wv = threadIdx.x >> 6;
    if (lane == 0) { redm[wv] = ms; redc[wv] = cnt; }
    __syncthreads();
    if (threadIdx.x == 0) {
        atomicAdd(scr + 1, redm[0] + redm[1] + redm[2] + redm[3]);
        atomicAdd(scr + 2, redc[0] + redc[1] + redc[2] + redc[3]);
    }
}

__global__ void tern_write(const float* __restrict__ w, int n,
                           const double* __restrict__ scr,
                           float* __restrict__ wt) {
    const float delta = (float)(0.7 * scr[0] / (double)n);
    const double c = scr[2];
    const float alpha = (float)(scr[1] / (c > 1.0 ? c : 1.0));
    for (int i = blockIdx.x * blockDim.x + threadIdx.x; i < n;
         i += gridDim.x * blockDim.x) {
        float v = w[i];
        wt[i] = (fabsf(v) > delta) ? (v > 0.0f ? alpha : -alpha) : 0.0f;
    }
}

// ---------------------------------------------------------------------------
// Fused conv3x3(pad1)+bias+relu+maxpool2.
// Thread: 1 pooled pixel x NCO output channels. Block: BIMG images x one
// NCO-chunk of co. Weights in LDS padded to 12 floats per (co,ci) so the
// 9 taps read back as 3x float4 broadcast (all threads same addr -> free).
// ---------------------------------------------------------------------------
template <int CI, int HI, int CO, int NCO, int BIMG>
__global__ __launch_bounds__(256) void conv_pool2(
        const float* __restrict__ x, const float* __restrict__ wt,
        const float* __restrict__ bias, float* __restrict__ y) {
    constexpr int PO = HI / 2;
    constexpr int NPX = PO * PO;
    static_assert(BIMG * NPX == 256, "block must be 256 threads");

    const int co0 = blockIdx.y * NCO;
    const int b0 = blockIdx.x * BIMG;

    __shared__ float sw[NCO * CI * 12];
    for (int i = threadIdx.x; i < NCO * CI * 9; i += 256) {
        const int c = i / (CI * 9);
        const int r = i % (CI * 9);
        const int ci = r / 9, k = r % 9;
        sw[(c * CI + ci) * 12 + k] = wt[((long)(co0 + c) * CI + ci) * 9 + k];
    }
    __syncthreads();

    const int bl = threadIdx.x / NPX;
    const int px = threadIdx.x % NPX;
    const int ph = px / PO, pw = px % PO;
    const int b = b0 + bl;
    const int h0 = 2 * ph, w0 = 2 * pw;

    float acc[NCO][4];
    #pragma unroll
    for (int c = 0; c < NCO; c++)
        #pragma unroll
        for (int q = 0; q < 4; q++) acc[c][q] = 0.f;

    const float* xb = x + (long)b * CI * HI * HI;
    for (int ci = 0; ci < CI; ci++) {
        const float* xc = xb + ci * HI * HI;
        float p[4][4];
        #pragma unroll
        for (int r = 0; r < 4; r++) {
            const int h = h0 - 1 + r;
            const bool hin = (unsigned)h < (unsigned)HI;
            #pragma unroll
            for (int c2 = 0; c2 < 4; c2++) {
                const int w = w0 - 1 + c2;
                p[r][c2] = (hin && (unsigned)w < (unsigned)HI)
                               ? xc[h * HI + w] : 0.f;
            }
        }
        #pragma unroll
        for (int c = 0; c < NCO; c++) {
            const float4* w4 = (const float4*)(sw + (c * CI + ci) * 12);
            const float4 wa = w4[0], wb = w4[1], wc = w4[2];
            const float wk[9] = {wa.x, wa.y, wa.z, wa.w,
                                 wb.x, wb.y, wb.z, wb.w, wc.x};
            #pragma unroll
            for (int kh = 0; kh < 3; kh++)
                #pragma unroll
                for (int kw = 0; kw < 3; kw++) {
                    const float wvv = wk[kh * 3 + kw];
                    acc[c][0] += wvv * p[kh][kw];
                    acc[c][1] += wvv * p[kh][kw + 1];
                    acc[c][2] += wvv * p[kh + 1][kw];
                    acc[c][3] += wvv * p[kh + 1][kw + 1];
                }
        }
    }

    #pragma unroll
    for (int c = 0; c < NCO; c++) {
        float m = fmaxf(fmaxf(acc[c][0], acc[c][1]),
                        fmaxf(acc[c][2], acc[c][3]));
        m = fmaxf(m + bias[co0 + c], 0.f);
        y[((long)b * CO + co0 + c) * NPX + px] = m;
    }
}

// ---------------------------------------------------------------------------
// FC1: 2 images per block; x-rows in LDS; thread j owns weight row j and
// produces out[b0][j], out[b0+1][j] (8 FMA per float4 weight load).
// ---------------------------------------------------------------------------
__global__ __launch_bounds__(256) void fc1_kernel(
        const float* __restrict__ a, const float* __restrict__ wt,
        const float* __restrict__ bias, float* __restrict__ out) {
    __shared__ float sx[2][4096];
    const int b0 = blockIdx.x * 2;
    for (int i = threadIdx.x; i < 2 * 4096; i += 256)
        ((float*)sx)[i] = a[(long)b0 * 4096 + i];
    __syncthreads();
    const int j = threadIdx.x;
    const float4* wr = (const float4*)(wt + (long)j * 4096);
    const float4* x0 = (const float4*)sx[0];
    const float4* x1 = (const float4*)sx[1];
    float a0 = 0.f, a1 = 0.f;
    #pragma unroll 4
    for (int i = 0; i < 1024; i++) {
        const float4 w4 = wr[i];
        const float4 v0 = x0[i];
        const float4 v1 = x1[i];
        a0 += w4.x * v0.x + w4.y * v0.y + w4.z * v0.z + w4.w * v0.w;
        a1 += w4.x * v1.x + w4.y * v1.y + w4.z * v1.z + w4.w * v1.w;
    }
    const float bv = bias[j];
    out[(long)b0 * 256 + j]       = fmaxf(a0 + bv, 0.f);
    out[(long)(b0 + 1) * 256 + j] = fmaxf(a1 + bv, 0.f);
}

// ---------------------------------------------------------------------------
// FC2: out[b,k] = dot(a[b,:256], wt[k,:256]) + bias[k]
// ---------------------------------------------------------------------------
__global__ void fc2_kernel(const float* __restrict__ a,
                           const float* __restrict__ wt,
                           const float* __restrict__ bias,
                           float* __restrict__ out, int B) {
    const int idx = blockIdx.x * blockDim.x + threadIdx.x;
    if (idx >= B * 10) return;
    const int k = idx % 10;
    const int b = idx / 10;
    const float* ar = a + (long)b * 256;
    const float* wr = wt + (long)k * 256;
    float acc = 0.f;
    #pragma unroll 4
    for (int i = 0; i < 256; i++) acc += ar[i] * wr[i];
    out[idx] = acc + bias[k];
}

static inline int tern_grid(int n) {
    int g = (n + 255) / 256;
    return g > 128 ? 128 : g;
}

extern "C" void kernel_launch(void* const* d_in, const int* in_sizes, int n_in,
                              void* d_out, int out_size, void* d_ws, size_t ws_size,
                              hipStream_t stream) {
    const float* x   = (const float*)d_in[0];
    const float* w1  = (const float*)d_in[1];
    const float* b1  = (const float*)d_in[2];
    const float* w2  = (const float*)d_in[3];
    const float* b2  = (const float*)d_in[4];
    const float* w3  = (const float*)d_in[5];
    const float* b3  = (const float*)d_in[6];
    const float* wf1 = (const float*)d_in[7];
    const float* bf1 = (const float*)d_in[8];
    const float* wf2 = (const float*)d_in[9];
    const float* bf2 = (const float*)d_in[10];
    float* out = (float*)d_out;
    float* ws = (float*)d_ws;

    const int B = 1024;

    float* wt1  = ws + WS_WT1;
    float* wt2  = ws + WS_WT2;
    float* wt3  = ws + WS_WT3;
    float* wtf1 = ws + WS_WTF1;
    float* wtf2 = ws + WS_WTF2;
    float* a1   = ws + WS_A1;
    float* a2   = ws + WS_A2;
    float* a3   = ws + WS_A3;
    float* f1   = ws + WS_F1;
    double* scr = (double*)(ws + WS_SCR);   // 5 x 4 doubles

    hipMemsetAsync(scr, 0, 5 * 4 * sizeof(double), stream);

    const float* wsrc[5] = {w1, w2, w3, wf1, wf2};
    float* wdst[5] = {wt1, wt2, wt3, wtf1, wtf2};
    const int wn[5] = {N_WT1, N_WT2, N_WT3, N_WTF1, N_WTF2};
    for (int i = 0; i < 5; i++) {
        const int g = tern_grid(wn[i]);
        hipLaunchKernelGGL(tern_sum_abs, dim3(g), dim3(256), 0, stream,
                           wsrc[i], wn[i], scr + 4 * i);
        hipLaunchKernelGGL(tern_masked, dim3(g), dim3(256), 0, stream,
                           wsrc[i], wn[i], scr + 4 * i);
        hipLaunchKernelGGL(tern_write, dim3(g), dim3(256), 0, stream,
                           wsrc[i], wn[i], scr + 4 * i, wdst[i]);
    }

    // conv1: CI=3, HI=32, CO=64, NCO=8, BIMG=1   -> grid 1024 x 8
    hipLaunchKernelGGL((conv_pool2<3, 32, 64, 8, 1>),
                       dim3(B, 64 / 8), dim3(256), 0, stream, x, wt1, b1, a1);
    // conv2: CI=64, HI=16, CO=128, NCO=8, BIMG=4 -> grid 256 x 16
    hipLaunchKernelGGL((conv_pool2<64, 16, 128, 8, 4>),
                       dim3(B / 4, 128 / 8), dim3(256), 0, stream, a1, wt2, b2, a2);
    // conv3: CI=128, HI=8, CO=256, NCO=8, BIMG=16 -> grid 64 x 32
    hipLaunchKernelGGL((conv_pool2<128, 8, 256, 8, 16>),
                       dim3(B / 16, 256 / 8), dim3(256), 0, stream, a2, wt3, b3, a3);

    // FC1 + relu (2 images per block)
    hipLaunchKernelGGL(fc1_kernel, dim3(B / 2), dim3(256), 0, stream,
                       a3, wtf1, bf1, f1);

    // FC2
    hipLaunchKernelGGL(fc2_kernel, dim3((B * 10 + 255) / 256), dim3(256), 0,
                       stream, f1, wtf2, bf2, out, B);
}

// Round 3
// 789.568 us; speedup vs baseline: 18.9595x; 2.3044x over previous
//
#include <hip/hip_runtime.h>
#include <hip/hip_bf16.h>

// ---------------------------------------------------------------------------
// TernaryCIFAR10Net on MI355X — Round 3: bf16 MFMA convs with exact hi/lo
// activation split (ternary sign matrix is exact in bf16).
//   conv1: fp32 direct (CI=3), emits NHWC bf16(hi,lo)-pair activations
//   conv2/conv3: 9-tap implicit GEMM, mfma_f32_16x16x32_bf16
//     A = activations from padded LDS image (ds_read_b128, native layout)
//     B = sign weights [tap][co][ci'] streamed from global (L2-resident)
//     pixel swizzle m = pp*4+sub  => 2x2 maxpool is register-local (C/D regs)
//   fc1: consumes conv3 NHWC layout via permuted ternarized wf1
// ---------------------------------------------------------------------------

typedef __attribute__((ext_vector_type(8))) short short8;
typedef __attribute__((ext_vector_type(4))) float f32x4;

__device__ __forceinline__ unsigned short f2bf(float x) {
    unsigned u = __float_as_uint(x);
    return (unsigned short)((u + 0x7fffu + ((u >> 16) & 1u)) >> 16);  // RNE
}
__device__ __forceinline__ float bf2f(unsigned short b) {
    return __uint_as_float(((unsigned)b) << 16);
}

// workspace layout (4-byte units)
#define WS_WT1   0
#define N_WT1    (64*3*3*3)            // 1728 fp32
#define WS_W2P   (WS_WT1 + N_WT1)
#define N_W2P    (9*128*64)            // u32 sign-pairs [tap][co][ci]
#define WS_W3P   (WS_W2P + N_W2P)
#define N_W3P    (9*256*128)
#define WS_WTF1  (WS_W3P + N_W3P)
#define N_WTF1   (256*4096)            // fp32, permuted
#define WS_WTF2  (WS_WTF1 + N_WTF1)
#define N_WTF2   (10*256)
#define WS_A1    (WS_WTF2 + N_WTF2)
#define N_A1     (1024*256*64)         // u32 (hi,lo) NHWC
#define WS_A2    (WS_A1 + N_A1)
#define N_A2     (1024*64*128)
#define WS_A3    (WS_A2 + N_A2)
#define N_A3     (1024*16*256)
#define WS_F1    (WS_A3 + N_A3)
#define N_F1     (1024*256)
#define WS_SCR   (WS_F1 + N_F1)        // 5 x 4 doubles

// ---------------------------------------------------------------------------
// Ternarize stats: scr = {sum|w|, masked_sum, count, pad} (doubles, memset 0)
// ---------------------------------------------------------------------------
__global__ void tern_sum_abs(const float* __restrict__ w, int n,
                             double* __restrict__ scr) {
    double s = 0.0;
    for (int i = blockIdx.x * blockDim.x + threadIdx.x; i < n;
         i += gridDim.x * blockDim.x)
        s += (double)fabsf(w[i]);
    #pragma unroll
    for (int off = 32; off > 0; off >>= 1) s += __shfl_down(s, off, 64);
    __shared__ double red[4];
    const int lane = threadIdx.x & 63, wv = threadIdx.x >> 6;
    if (lane == 0) red[wv] = s;
    __syncthreads();
    if (threadIdx.x == 0) atomicAdd(scr, red[0] + red[1] + red[2] + red[3]);
}

__global__ void tern_masked(const float* __restrict__ w, int n,
                            double* __restrict__ scr) {
    const float delta = (float)(0.7 * scr[0] / (double)n);
    double ms = 0.0, cnt = 0.0;
    for (int i = blockIdx.x * blockDim.x + threadIdx.x; i < n;
         i += gridDim.x * blockDim.x) {
        float a = fabsf(w[i]);
        if (a > delta) { ms += (double)a; cnt += 1.0; }
    }
    #pragma unroll
    for (int off = 32; off > 0; off >>= 1) {
        ms += __shfl_down(ms, off, 64);
        cnt += __shfl_down(cnt, off, 64);
    }
    __shared__ double redm[4], redc[4];
    const int lane = threadIdx.x & 63, wv = threadIdx.x >> 6;
    if (lane == 0) { redm[wv] = ms; redc[wv] = cnt; }
    __syncthreads();
    if (threadIdx.x == 0) {
        atomicAdd(scr + 1, redm[0] + redm[1] + redm[2] + redm[3]);
        atomicAdd(scr + 2, redc[0] + redc[1] + redc[2] + redc[3]);
    }
}

// plain fp32 alpha*sign (w1, wf2)
__global__ void tern_write(const float* __restrict__ w, int n,
                           const double* __restrict__ scr,
                           float* __restrict__ wt) {
    const float delta = (float)(0.7 * scr[0] / (double)n);
    const double c = scr[2];
    const float alpha = (float)(scr[1] / (c > 1.0 ? c : 1.0));
    for (int i = blockIdx.x * blockDim.x + threadIdx.x; i < n;
         i += gridDim.x * blockDim.x) {
        float v = w[i];
        wt[i] = (fabsf(v) > delta) ? (v > 0.0f ? alpha : -alpha) : 0.0f;
    }
}

// conv sign pack: src [CO][CI][3][3] -> dst u32 [tap][co][ci], pair(s,s) bf16
__global__ void tern_pack_conv(const float* __restrict__ w, int CO, int CI,
                               const double* __restrict__ scr,
                               unsigned* __restrict__ dst) {
    const int n = CO * CI * 9;
    const float delta = (float)(0.7 * scr[0] / (double)n);
    for (int i = blockIdx.x * blockDim.x + threadIdx.x; i < n;
         i += gridDim.x * blockDim.x) {
        const int co = i / (CI * 9);
        const int r = i % (CI * 9);
        const int ci = r / 9, tap = r % 9;
        float v = w[i];
        unsigned short s = (fabsf(v) > delta) ? (v > 0.0f ? 0x3f80 : 0xbf80) : 0;
        dst[((tap * CO + co) * CI) + ci] = (unsigned)s | ((unsigned)s << 16);
    }
}

// fc1 weights: permute k = c*16+px  ->  px*256+c  (a3' is [px][c]); scaled fp32
__global__ void tern_write_fc1(const float* __restrict__ w,
                               const double* __restrict__ scr,
                               float* __restrict__ dst) {
    const int n = 256 * 4096;
    const float delta = (float)(0.7 * scr[0] / (double)n);
    const double c2 = scr[2];
    const float alpha = (float)(scr[1] / (c2 > 1.0 ? c2 : 1.0));
    for (int i = blockIdx.x * blockDim.x + threadIdx.x; i < n;
         i += gridDim.x * blockDim.x) {
        const int j = i >> 12;
        const int k = i & 4095;
        const int c = k >> 4, px = k & 15;
        float v = w[i];
        float t = (fabsf(v) > delta) ? (v > 0.0f ? alpha : -alpha) : 0.0f;
        dst[(j << 12) + px * 256 + c] = t;
    }
}

// ---------------------------------------------------------------------------
// conv1: fp32 direct (CI=3), fused bias+relu+pool, output NHWC u32(hi,lo)
// ---------------------------------------------------------------------------
__global__ __launch_bounds__(256) void conv1_kernel(
        const float* __restrict__ x, const float* __restrict__ wt,
        const float* __restrict__ bias, unsigned* __restrict__ y) {
    constexpr int CI = 3, HI = 32, CO = 64, NCO = 8, PO = 16, NPX = 256;
    const int co0 = blockIdx.y * NCO;
    __shared__ float sw[NCO * CI * 12];
    for (int i = threadIdx.x; i < NCO * CI * 9; i += 256) {
        const int c = i / (CI * 9);
        const int r = i % (CI * 9);
        const int ci = r / 9, k = r % 9;
        sw[(c * CI + ci) * 12 + k] = wt[((long)(co0 + c) * CI + ci) * 9 + k];
    }
    __syncthreads();

    const int px = threadIdx.x;              // 256 = one full pooled image
    const int b = blockIdx.x;
    const int ph = px / PO, pw = px % PO;
    const int h0 = 2 * ph, w0 = 2 * pw;

    float acc[NCO][4];
    #pragma unroll
    for (int c = 0; c < NCO; c++)
        #pragma unroll
        for (int q = 0; q < 4; q++) acc[c][q] = 0.f;

    const float* xb = x + (long)b * CI * HI * HI;
    for (int ci = 0; ci < CI; ci++) {
        const float* xc = xb + ci * HI * HI;
        float p[4][4];
        #pragma unroll
        for (int r = 0; r < 4; r++) {
            const int h = h0 - 1 + r;
            const bool hin = (unsigned)h < (unsigned)HI;
            #pragma unroll
            for (int c2 = 0; c2 < 4; c2++) {
                const int w = w0 - 1 + c2;
                p[r][c2] = (hin && (unsigned)w < (unsigned)HI) ? xc[h * HI + w] : 0.f;
            }
        }
        #pragma unroll
        for (int c = 0; c < NCO; c++) {
            const float4* w4 = (const float4*)(sw + (c * CI + ci) * 12);
            const float4 wa = w4[0], wb = w4[1], wc = w4[2];
            const float wk[9] = {wa.x, wa.y, wa.z, wa.w, wb.x, wb.y, wb.z, wb.w, wc.x};
            #pragma unroll
            for (int kh = 0; kh < 3; kh++)
                #pragma unroll
                for (int kw = 0; kw < 3; kw++) {
                    const float wvv = wk[kh * 3 + kw];
                    acc[c][0] += wvv * p[kh][kw];
                    acc[c][1] += wvv * p[kh][kw + 1];
                    acc[c][2] += wvv * p[kh + 1][kw];
                    acc[c][3] += wvv * p[kh + 1][kw + 1];
                }
        }
    }
    #pragma unroll
    for (int c = 0; c < NCO; c++) {
        float m = fmaxf(fmaxf(acc[c][0], acc[c][1]), fmaxf(acc[c][2], acc[c][3]));
        float o = fmaxf(m + bias[co0 + c], 0.f);
        unsigned short hi = f2bf(o);
        unsigned short lo = f2bf(o - bf2f(hi));
        y[((long)b * NPX + px) * CO + co0 + c] = (unsigned)hi | ((unsigned)lo << 16);
    }
}

// ---------------------------------------------------------------------------
// MFMA conv: input NHWC u32(hi,lo) pairs; ci' = 2*CI bf16 per pixel.
// Block: one image (HB=1) or half rows (HB=2). 4 waves, wave tile 64px x 64co.
// Zero-padded LDS image, pixel pitch CI2+8 (bank stride 4 -> 2-way, free).
// ---------------------------------------------------------------------------
template <int CI2, int HI, int CO, int HB>
__global__ __launch_bounds__(256) void conv_mfma(
        const unsigned* __restrict__ xin,
        const unsigned short* __restrict__ wp,   // [9][CO][CI2] bf16 signs
        const float* __restrict__ bias,
        const double* __restrict__ scr,
        unsigned* __restrict__ yout) {
    constexpr int ROWS = HI / HB + 2;
    constexpr int COLS = HI + 2;
    constexpr int PITCH = CI2 + 8;               // bf16 units
    constexpr int NT = CO / 16;
    constexpr int WN = NT / 4;                   // waves along n
    constexpr int CH = CI2 / 32;                 // K-chunks per tap
    constexpr int PO = HI / 2;                   // pooled cols (full)
    constexpr int POR = (HI / HB) / 2;           // pooled rows per block
    constexpr int NITER = 9 * CH;

    __shared__ unsigned short X[ROWS * COLS * PITCH];

    const int bimg = blockIdx.x / HB;
    const int hb = blockIdx.x % HB;
    const int tid = threadIdx.x;

    // zero LDS (covers borders + pads)
    constexpr int NQZ = ROWS * COLS * PITCH * 2 / 16;
    for (int i = tid; i < NQZ; i += 256) ((int4*)X)[i] = make_int4(0, 0, 0, 0);
    __syncthreads();

    // copy interior rows (coalesced uint4)
    constexpr int QPP = CI2 / 8;                 // uint4 per pixel
    for (int i = tid; i < ROWS * HI * QPP; i += 256) {
        const int q = i % QPP;
        const int t = i / QPP;
        const int c = t % HI;
        const int r = t / HI;
        const int h = hb * (HI / HB) + r - 1;
        if ((unsigned)h < (unsigned)HI) {
            const uint4 v = ((const uint4*)(xin +
                ((long)(bimg * HI + h) * HI + c) * (CI2 / 2)))[q];
            *(uint4*)&X[(r * COLS + c + 1) * PITCH + q * 8] = v;
        }
    }
    __syncthreads();

    const int lane = tid & 63;
    const int wid = tid >> 6;
    const int wm = wid / WN;
    const int wn = wid % WN;
    const int lm = lane & 15;
    const int kg = lane >> 4;

    // per-lane A bases: pixel swizzle m = pp*4 + sub  (pool-local in regs)
    int abase[4];
    #pragma unroll
    for (int mt = 0; mt < 4; mt++) {
        const int m = (wm * 4 + mt) * 16 + lm;
        const int pp = m >> 2, sub = m & 3;
        const int lph = pp / PO, lpw = pp % PO;
        const int h = 2 * lph + (sub >> 1);
        const int w = 2 * lpw + (sub & 1);
        abase[mt] = (h * COLS + w) * PITCH + kg * 8;
    }
    const long bco = (long)(wn * 64 + lm) * CI2 + kg * 8;

    f32x4 acc[4][4] = {};
    short8 Bc[4], Bn[4];
    #pragma unroll
    for (int nt = 0; nt < 4; nt++)
        Bc[nt] = *(const short8*)(wp + bco + (long)nt * 16 * CI2);

    for (int it = 0; it < NITER; ++it) {
        const int tap = it / CH, ch = it % CH;
        const int dh = tap / 3, dw = tap % 3;
        const int toff = (dh * COLS + dw) * PITCH + ch * 32;
        short8 Af[4];
        #pragma unroll
        for (int mt = 0; mt < 4; mt++)
            Af[mt] = *(const short8*)&X[abase[mt] + toff];
        if (it + 1 < NITER) {
            const int tap2 = (it + 1) / CH, ch2 = (it + 1) % CH;
            const long woff = (long)(tap2 * CO) * CI2 + ch2 * 32 + bco;
            #pragma unroll
            for (int nt = 0; nt < 4; nt++)
                Bn[nt] = *(const short8*)(wp + woff + (long)nt * 16 * CI2);
        }
        #pragma unroll
        for (int mt = 0; mt < 4; mt++)
            #pragma unroll
            for (int nt = 0; nt < 4; nt++)
                acc[mt][nt] = __builtin_amdgcn_mfma_f32_16x16x32_bf16(
                    Af[mt], Bc[nt], acc[mt][nt], 0, 0, 0);
        #pragma unroll
        for (int nt = 0; nt < 4; nt++) Bc[nt] = Bn[nt];
    }

    // epilogue: regs of each lane = the 2x2 pool members of pooled pixel pp
    const double c2 = scr[2];
    const float alpha = (float)(scr[1] / (c2 > 1.0 ? c2 : 1.0));
    #pragma unroll
    for (int mt = 0; mt < 4; mt++) {
        const int pp = (wm * 4 + mt) * 4 + kg;
        const int lph = pp / PO, lpw = pp % PO;
        const int gpp = (hb * POR + lph) * PO + lpw;
        #pragma unroll
        for (int nt = 0; nt < 4; nt++) {
            const int co = (wn * 4 + nt) * 16 + lm;
            const f32x4 a = acc[mt][nt];
            float v = fmaxf(fmaxf(a[0], a[1]), fmaxf(a[2], a[3]));
            float o = fmaxf(alpha * v + bias[co], 0.f);
            unsigned short hi = f2bf(o);
            unsigned short lo = f2bf(o - bf2f(hi));
            yout[((long)bimg * (PO * PO) + gpp) * CO + co] =
                (unsigned)hi | ((unsigned)lo << 16);
        }
    }
}

// ---------------------------------------------------------------------------
// FC1: 2 images/block; unpack hi/lo pairs to fp32 in LDS; permuted weights
// ---------------------------------------------------------------------------
__global__ __launch_bounds__(256) void fc1_kernel(
        const unsigned* __restrict__ a3p, const float* __restrict__ wt,
        const float* __restrict__ bias, float* __restrict__ out) {
    __shared__ float sx[2][4096];
    const long b0 = (long)blockIdx.x * 2;
    for (int i = threadIdx.x; i < 8192; i += 256) {
        const unsigned u = a3p[b0 * 4096 + i];
        ((float*)sx)[i] = bf2f((unsigned short)(u & 0xffff)) +
                          bf2f((unsigned short)(u >> 16));
    }
    __syncthreads();
    const int j = threadIdx.x;
    const float4* wr = (const float4*)(wt + (long)j * 4096);
    const float4* x0 = (const float4*)sx[0];
    const float4* x1 = (const float4*)sx[1];
    float a0 = 0.f, a1 = 0.f;
    #pragma unroll 4
    for (int i = 0; i < 1024; i++) {
        const float4 w4 = wr[i];
        const float4 v0 = x0[i];
        const float4 v1 = x1[i];
        a0 += w4.x * v0.x + w4.y * v0.y + w4.z * v0.z + w4.w * v0.w;
        a1 += w4.x * v1.x + w4.y * v1.y + w4.z * v1.z + w4.w * v1.w;
    }
    const float bv = bias[j];
    out[b0 * 256 + j] = fmaxf(a0 + bv, 0.f);
    out[(b0 + 1) * 256 + j] = fmaxf(a1 + bv, 0.f);
}

__global__ void fc2_kernel(const float* __restrict__ a,
                           const float* __restrict__ wt,
                           const float* __restrict__ bias,
                           float* __restrict__ out, int B) {
    const int idx = blockIdx.x * blockDim.x + threadIdx.x;
    if (idx >= B * 10) return;
    const int k = idx % 10;
    const int b = idx / 10;
    const float* ar = a + (long)b * 256;
    const float* wr = wt + (long)k * 256;
    float acc = 0.f;
    #pragma unroll 4
    for (int i = 0; i < 256; i++) acc += ar[i] * wr[i];
    out[idx] = acc + bias[k];
}

static inline int tern_grid(int n) {
    int g = (n + 255) / 256;
    return g > 128 ? 128 : g;
}

extern "C" void kernel_launch(void* const* d_in, const int* in_sizes, int n_in,
                              void* d_out, int out_size, void* d_ws, size_t ws_size,
                              hipStream_t stream) {
    const float* x   = (const float*)d_in[0];
    const float* w1  = (const float*)d_in[1];
    const float* b1  = (const float*)d_in[2];
    const float* w2  = (const float*)d_in[3];
    const float* b2  = (const float*)d_in[4];
    const float* w3  = (const float*)d_in[5];
    const float* b3  = (const float*)d_in[6];
    const float* wf1 = (const float*)d_in[7];
    const float* bf1 = (const float*)d_in[8];
    const float* wf2 = (const float*)d_in[9];
    const float* bf2 = (const float*)d_in[10];
    float* out = (float*)d_out;
    float* ws = (float*)d_ws;

    const int B = 1024;

    float*    wt1   = ws + WS_WT1;
    unsigned* w2p   = (unsigned*)(ws + WS_W2P);
    unsigned* w3p   = (unsigned*)(ws + WS_W3P);
    float*    wtf1p = ws + WS_WTF1;
    float*    wtf2  = ws + WS_WTF2;
    unsigned* a1p   = (unsigned*)(ws + WS_A1);
    unsigned* a2p   = (unsigned*)(ws + WS_A2);
    unsigned* a3p   = (unsigned*)(ws + WS_A3);
    float*    f1    = ws + WS_F1;
    double*   scr   = (double*)(ws + WS_SCR);

    hipMemsetAsync(scr, 0, 5 * 4 * sizeof(double), stream);

    // stats for all 5 weights
    const float* wsrc[5] = {w1, w2, w3, wf1, wf2};
    const int wn[5] = {N_WT1, 128 * 64 * 9, 256 * 128 * 9, 256 * 4096, 10 * 256};
    for (int i = 0; i < 5; i++) {
        const int g = tern_grid(wn[i]);
        hipLaunchKernelGGL(tern_sum_abs, dim3(g), dim3(256), 0, stream,
                           wsrc[i], wn[i], scr + 4 * i);
        hipLaunchKernelGGL(tern_masked, dim3(g), dim3(256), 0, stream,
                           wsrc[i], wn[i], scr + 4 * i);
    }
    // writers
    hipLaunchKernelGGL(tern_write, dim3(tern_grid(wn[0])), dim3(256), 0, stream,
                       w1, wn[0], scr + 0, wt1);
    hipLaunchKernelGGL(tern_pack_conv, dim3(tern_grid(wn[1])), dim3(256), 0, stream,
                       w2, 128, 64, scr + 4, w2p);
    hipLaunchKernelGGL(tern_pack_conv, dim3(tern_grid(wn[2])), dim3(256), 0, stream,
                       w3, 256, 128, scr + 8, w3p);
    hipLaunchKernelGGL(tern_write_fc1, dim3(tern_grid(wn[3])), dim3(256), 0, stream,
                       wf1, scr + 12, wtf1p);
    hipLaunchKernelGGL(tern_write, dim3(tern_grid(wn[4])), dim3(256), 0, stream,
                       wf2, wn[4], scr + 16, wtf2);

    // conv1: fp32 direct -> a1p (NHWC hi/lo)
    hipLaunchKernelGGL(conv1_kernel, dim3(B, 8), dim3(256), 0, stream,
                       x, wt1, b1, a1p);

    // conv2: CI2=128, HI=16, CO=128, HB=2 -> 2048 blocks
    hipLaunchKernelGGL((conv_mfma<128, 16, 128, 2>), dim3(B * 2), dim3(256), 0,
                       stream, a1p, (const unsigned short*)w2p, b2, scr + 4, a2p);

    // conv3: CI2=256, HI=8, CO=256, HB=1 -> 1024 blocks
    hipLaunchKernelGGL((conv_mfma<256, 8, 256, 1>), dim3(B), dim3(256), 0,
                       stream, a2p, (const unsigned short*)w3p, b3, scr + 8, a3p);

    // FC1 + relu
    hipLaunchKernelGGL(fc1_kernel, dim3(B / 2), dim3(256), 0, stream,
                       a3p, wtf1p, bf1, f1);

    // FC2
    hipLaunchKernelGGL(fc2_kernel, dim3((B * 10 + 255) / 256), dim3(256), 0,
                       stream, f1, wtf2, bf2, out, B);
}

// Round 4
// 555.817 us; speedup vs baseline: 26.9330x; 1.4206x over previous
//
#include <hip/hip_runtime.h>
#include <hip/hip_bf16.h>

// ---------------------------------------------------------------------------
// TernaryCIFAR10Net on MI355X — Round 4:
//   - fc1 -> bf16 MFMA GEMM (exact hi/lo split), split-K=16, partials aliased
//     onto the dead a1p workspace region; reduce kernel fuses alpha+bias+relu
//   - ternarize fused: 2 stats launches + 1 branching writer (was 15)
//   - conv1 fp32 direct, conv2/conv3 MFMA implicit-GEMM (unchanged from R3)
// ---------------------------------------------------------------------------

typedef __attribute__((ext_vector_type(8))) short short8;
typedef __attribute__((ext_vector_type(4))) float f32x4;

__device__ __forceinline__ unsigned short f2bf(float x) {
    unsigned u = __float_as_uint(x);
    return (unsigned short)((u + 0x7fffu + ((u >> 16) & 1u)) >> 16);  // RNE
}
__device__ __forceinline__ float bf2f(unsigned short b) {
    return __uint_as_float(((unsigned)b) << 16);
}

// workspace layout (4-byte units)
#define WS_WT1   0
#define N_WT1    (64*3*3*3)            // 1728 fp32
#define WS_W2P   (WS_WT1 + N_WT1)
#define N_W2P    (9*128*64)            // u32 sign-pairs [tap][co][ci]
#define WS_W3P   (WS_W2P + N_W2P)
#define N_W3P    (9*256*128)
#define WS_WTF1  (WS_W3P + N_W3P)
#define N_WTF1   (256*4096)            // u32 sign-pairs [j][px*256+c]
#define WS_WTF2  (WS_WTF1 + N_WTF1)
#define N_WTF2   (10*256)
#define WS_A1    (WS_WTF2 + N_WTF2)
#define N_A1     (1024*256*64)         // u32 (hi,lo) NHWC; ALSO fc1 parts alias
#define WS_A2    (WS_A1 + N_A1)
#define N_A2     (1024*64*128)
#define WS_A3    (WS_A2 + N_A2)
#define N_A3     (1024*16*256)
#define WS_F1    (WS_A3 + N_A3)
#define N_F1     (1024*256)
#define WS_SCR   (WS_F1 + N_F1)        // 5 x 4 doubles

#define FC1_S    16                    // split-K factor

struct TernArgs {
    const float* w[5];
    int n[5];
};

// ---------------------------------------------------------------------------
// Fused ternarize stats: grid (g, 5). scr[wi] = {sum|w|, masked_sum, count}.
// ---------------------------------------------------------------------------
__global__ void tern_stats1(TernArgs ta, double* __restrict__ scr) {
    const int wi = blockIdx.y;
    const float* __restrict__ w = ta.w[wi];
    const int n = ta.n[wi];
    double s = 0.0;
    for (int i = blockIdx.x * blockDim.x + threadIdx.x; i < n;
         i += gridDim.x * blockDim.x)
        s += (double)fabsf(w[i]);
    #pragma unroll
    for (int off = 32; off > 0; off >>= 1) s += __shfl_down(s, off, 64);
    __shared__ double red[4];
    const int lane = threadIdx.x & 63, wv = threadIdx.x >> 6;
    if (lane == 0) red[wv] = s;
    __syncthreads();
    if (threadIdx.x == 0)
        atomicAdd(scr + wi * 4, red[0] + red[1] + red[2] + red[3]);
}

__global__ void tern_stats2(TernArgs ta, double* __restrict__ scr) {
    const int wi = blockIdx.y;
    const float* __restrict__ w = ta.w[wi];
    const int n = ta.n[wi];
    const float delta = (float)(0.7 * scr[wi * 4] / (double)n);
    double ms = 0.0, cnt = 0.0;
    for (int i = blockIdx.x * blockDim.x + threadIdx.x; i < n;
         i += gridDim.x * blockDim.x) {
        float a = fabsf(w[i]);
        if (a > delta) { ms += (double)a; cnt += 1.0; }
    }
    #pragma unroll
    for (int off = 32; off > 0; off >>= 1) {
        ms += __shfl_down(ms, off, 64);
        cnt += __shfl_down(cnt, off, 64);
    }
    __shared__ double redm[4], redc[4];
    const int lane = threadIdx.x & 63, wv = threadIdx.x >> 6;
    if (lane == 0) { redm[wv] = ms; redc[wv] = cnt; }
    __syncthreads();
    if (threadIdx.x == 0) {
        atomicAdd(scr + wi * 4 + 1, redm[0] + redm[1] + redm[2] + redm[3]);
        atomicAdd(scr + wi * 4 + 2, redc[0] + redc[1] + redc[2] + redc[3]);
    }
}

// ---------------------------------------------------------------------------
// Fused writer: grid (g, 5); uniform branch per weight id.
//   0: w1  -> wt1 fp32 alpha*sign
//   1: w2  -> w2p  u32 sign-pairs [tap][co][ci]   (CO=128, CI=64)
//   2: w3  -> w3p  u32 sign-pairs                 (CO=256, CI=128)
//   3: wf1 -> wtf1b u32 sign-pairs [j][px*256+c]  (matches a3p interleave)
//   4: wf2 -> wtf2 fp32 alpha*sign
// ---------------------------------------------------------------------------
__global__ void tern_write_all(TernArgs ta, const double* __restrict__ scr,
                               float* __restrict__ wt1,
                               unsigned* __restrict__ w2p,
                               unsigned* __restrict__ w3p,
                               unsigned* __restrict__ wtf1b,
                               float* __restrict__ wtf2) {
    const int wi = blockIdx.y;
    const float* __restrict__ w = ta.w[wi];
    const int n = ta.n[wi];
    const double* sc = scr + wi * 4;
    const float delta = (float)(0.7 * sc[0] / (double)n);
    const int i0 = blockIdx.x * blockDim.x + threadIdx.x;
    const int stride = gridDim.x * blockDim.x;

    if (wi == 0 || wi == 4) {
        const double c = sc[2];
        const float alpha = (float)(sc[1] / (c > 1.0 ? c : 1.0));
        float* dst = (wi == 0) ? wt1 : wtf2;
        for (int i = i0; i < n; i += stride) {
            float v = w[i];
            dst[i] = (fabsf(v) > delta) ? (v > 0.0f ? alpha : -alpha) : 0.0f;
        }
    } else if (wi == 1 || wi == 2) {
        const int CI = (wi == 1) ? 64 : 128;
        const int CO = (wi == 1) ? 128 : 256;
        unsigned* dst = (wi == 1) ? w2p : w3p;
        for (int i = i0; i < n; i += stride) {
            const int co = i / (CI * 9);
            const int r = i % (CI * 9);
            const int ci = r / 9, tap = r % 9;
            float v = w[i];
            unsigned short s = (fabsf(v) > delta) ? (v > 0.0f ? 0x3f80 : 0xbf80) : 0;
            dst[(tap * CO + co) * CI + ci] = (unsigned)s | ((unsigned)s << 16);
        }
    } else {  // wi == 3: fc1 signs, permuted + duplicated for hi/lo interleave
        for (int i = i0; i < n; i += stride) {
            const int j = i >> 12;
            const int k = i & 4095;
            const int c = k >> 4, px = k & 15;
            float v = w[i];
            unsigned short s = (fabsf(v) > delta) ? (v > 0.0f ? 0x3f80 : 0xbf80) : 0;
            wtf1b[(j << 12) + px * 256 + c] = (unsigned)s | ((unsigned)s << 16);
        }
    }
}

// ---------------------------------------------------------------------------
// conv1: fp32 direct (CI=3), fused bias+relu+pool, output NHWC u32(hi,lo)
// ---------------------------------------------------------------------------
__global__ __launch_bounds__(256) void conv1_kernel(
        const float* __restrict__ x, const float* __restrict__ wt,
        const float* __restrict__ bias, unsigned* __restrict__ y) {
    constexpr int CI = 3, HI = 32, CO = 64, NCO = 8, PO = 16, NPX = 256;
    const int co0 = blockIdx.y * NCO;
    __shared__ float sw[NCO * CI * 12];
    for (int i = threadIdx.x; i < NCO * CI * 9; i += 256) {
        const int c = i / (CI * 9);
        const int r = i % (CI * 9);
        const int ci = r / 9, k = r % 9;
        sw[(c * CI + ci) * 12 + k] = wt[((long)(co0 + c) * CI + ci) * 9 + k];
    }
    __syncthreads();

    const int px = threadIdx.x;
    const int b = blockIdx.x;
    const int ph = px / PO, pw = px % PO;
    const int h0 = 2 * ph, w0 = 2 * pw;

    float acc[NCO][4];
    #pragma unroll
    for (int c = 0; c < NCO; c++)
        #pragma unroll
        for (int q = 0; q < 4; q++) acc[c][q] = 0.f;

    const float* xb = x + (long)b * CI * HI * HI;
    for (int ci = 0; ci < CI; ci++) {
        const float* xc = xb + ci * HI * HI;
        float p[4][4];
        #pragma unroll
        for (int r = 0; r < 4; r++) {
            const int h = h0 - 1 + r;
            const bool hin = (unsigned)h < (unsigned)HI;
            #pragma unroll
            for (int c2 = 0; c2 < 4; c2++) {
                const int w = w0 - 1 + c2;
                p[r][c2] = (hin && (unsigned)w < (unsigned)HI) ? xc[h * HI + w] : 0.f;
            }
        }
        #pragma unroll
        for (int c = 0; c < NCO; c++) {
            const float4* w4 = (const float4*)(sw + (c * CI + ci) * 12);
            const float4 wa = w4[0], wb = w4[1], wc = w4[2];
            const float wk[9] = {wa.x, wa.y, wa.z, wa.w, wb.x, wb.y, wb.z, wb.w, wc.x};
            #pragma unroll
            for (int kh = 0; kh < 3; kh++)
                #pragma unroll
                for (int kw = 0; kw < 3; kw++) {
                    const float wvv = wk[kh * 3 + kw];
                    acc[c][0] += wvv * p[kh][kw];
                    acc[c][1] += wvv * p[kh][kw + 1];
                    acc[c][2] += wvv * p[kh + 1][kw];
                    acc[c][3] += wvv * p[kh + 1][kw + 1];
                }
        }
    }
    #pragma unroll
    for (int c = 0; c < NCO; c++) {
        float m = fmaxf(fmaxf(acc[c][0], acc[c][1]), fmaxf(acc[c][2], acc[c][3]));
        float o = fmaxf(m + bias[co0 + c], 0.f);
        unsigned short hi = f2bf(o);
        unsigned short lo = f2bf(o - bf2f(hi));
        y[((long)b * NPX + px) * CO + co0 + c] = (unsigned)hi | ((unsigned)lo << 16);
    }
}

// ---------------------------------------------------------------------------
// MFMA conv (unchanged from R3): NHWC u32(hi,lo) in, 9-tap implicit GEMM,
// register-local 2x2 maxpool via pixel swizzle, NHWC u32(hi,lo) out.
// ---------------------------------------------------------------------------
template <int CI2, int HI, int CO, int HB>
__global__ __launch_bounds__(256) void conv_mfma(
        const unsigned* __restrict__ xin,
        const unsigned short* __restrict__ wp,
        const float* __restrict__ bias,
        const double* __restrict__ scr,
        unsigned* __restrict__ yout) {
    constexpr int ROWS = HI / HB + 2;
    constexpr int COLS = HI + 2;
    constexpr int PITCH = CI2 + 8;
    constexpr int NT = CO / 16;
    constexpr int WN = NT / 4;
    constexpr int CH = CI2 / 32;
    constexpr int PO = HI / 2;
    constexpr int POR = (HI / HB) / 2;
    constexpr int NITER = 9 * CH;

    __shared__ unsigned short X[ROWS * COLS * PITCH];

    const int bimg = blockIdx.x / HB;
    const int hb = blockIdx.x % HB;
    const int tid = threadIdx.x;

    constexpr int NQZ = ROWS * COLS * PITCH * 2 / 16;
    for (int i = tid; i < NQZ; i += 256) ((int4*)X)[i] = make_int4(0, 0, 0, 0);
    __syncthreads();

    constexpr int QPP = CI2 / 8;
    for (int i = tid; i < ROWS * HI * QPP; i += 256) {
        const int q = i % QPP;
        const int t = i / QPP;
        const int c = t % HI;
        const int r = t / HI;
        const int h = hb * (HI / HB) + r - 1;
        if ((unsigned)h < (unsigned)HI) {
            const uint4 v = ((const uint4*)(xin +
                ((long)(bimg * HI + h) * HI + c) * (CI2 / 2)))[q];
            *(uint4*)&X[(r * COLS + c + 1) * PITCH + q * 8] = v;
        }
    }
    __syncthreads();

    const int lane = tid & 63;
    const int wid = tid >> 6;
    const int wm = wid / WN;
    const int wn = wid % WN;
    const int lm = lane & 15;
    const int kg = lane >> 4;

    int abase[4];
    #pragma unroll
    for (int mt = 0; mt < 4; mt++) {
        const int m = (wm * 4 + mt) * 16 + lm;
        const int pp = m >> 2, sub = m & 3;
        const int lph = pp / PO, lpw = pp % PO;
        const int h = 2 * lph + (sub >> 1);
        const int w = 2 * lpw + (sub & 1);
        abase[mt] = (h * COLS + w) * PITCH + kg * 8;
    }
    const long bco = (long)(wn * 64 + lm) * CI2 + kg * 8;

    f32x4 acc[4][4] = {};
    short8 Bc[4], Bn[4];
    #pragma unroll
    for (int nt = 0; nt < 4; nt++)
        Bc[nt] = *(const short8*)(wp + bco + (long)nt * 16 * CI2);

    for (int it = 0; it < NITER; ++it) {
        const int tap = it / CH, ch = it % CH;
        const int dh = tap / 3, dw = tap % 3;
        const int toff = (dh * COLS + dw) * PITCH + ch * 32;
        short8 Af[4];
        #pragma unroll
        for (int mt = 0; mt < 4; mt++)
            Af[mt] = *(const short8*)&X[abase[mt] + toff];
        if (it + 1 < NITER) {
            const int tap2 = (it + 1) / CH, ch2 = (it + 1) % CH;
            const long woff = (long)(tap2 * CO) * CI2 + ch2 * 32 + bco;
            #pragma unroll
            for (int nt = 0; nt < 4; nt++)
                Bn[nt] = *(const short8*)(wp + woff + (long)nt * 16 * CI2);
        }
        #pragma unroll
        for (int mt = 0; mt < 4; mt++)
            #pragma unroll
            for (int nt = 0; nt < 4; nt++)
                acc[mt][nt] = __builtin_amdgcn_mfma_f32_16x16x32_bf16(
                    Af[mt], Bc[nt], acc[mt][nt], 0, 0, 0);
        #pragma unroll
        for (int nt = 0; nt < 4; nt++) Bc[nt] = Bn[nt];
    }

    const double c2 = scr[2];
    const float alpha = (float)(scr[1] / (c2 > 1.0 ? c2 : 1.0));
    #pragma unroll
    for (int mt = 0; mt < 4; mt++) {
        const int pp = (wm * 4 + mt) * 4 + kg;
        const int lph = pp / PO, lpw = pp % PO;
        const int gpp = (hb * POR + lph) * PO + lpw;
        #pragma unroll
        for (int nt = 0; nt < 4; nt++) {
            const int co = (wn * 4 + nt) * 16 + lm;
            const f32x4 a = acc[mt][nt];
            float v = fmaxf(fmaxf(a[0], a[1]), fmaxf(a[2], a[3]));
            float o = fmaxf(alpha * v + bias[co], 0.f);
            unsigned short hi = f2bf(o);
            unsigned short lo = f2bf(o - bf2f(hi));
            yout[((long)bimg * (PO * PO) + gpp) * CO + co] =
                (unsigned)hi | ((unsigned)lo << 16);
        }
    }
}

// ---------------------------------------------------------------------------
// fc1 MFMA: C[b][j] = sum_k A[b][k]*S[j][k], A = a3p bf16 (hi,lo interleaved,
// K=8192), S = sign matrix. Block 128x128 (2x2 waves of 64x64), split-K.
// parts[s][b][j] fp32.
// ---------------------------------------------------------------------------
template <int S>
__global__ __launch_bounds__(256) void fc1_mfma(
        const unsigned* __restrict__ a3p,    // [1024][4096] u32
        const unsigned* __restrict__ wb,     // [256][4096] u32 sign-pairs
        float* __restrict__ parts) {         // [S][1024][256]
    constexpr int KCH = 8192 / S;
    constexpr int NSTEP = KCH / 32;
    const int m0 = blockIdx.x * 128;
    const int n0 = blockIdx.y * 128;
    const int s = blockIdx.z;
    const int tid = threadIdx.x;
    const int lane = tid & 63, wid = tid >> 6;
    const int wm = wid >> 1, wn = wid & 1;
    const int lm = lane & 15, kg = lane >> 4;

    const unsigned short* __restrict__ A = (const unsigned short*)a3p;
    const unsigned short* __restrict__ Bw = (const unsigned short*)wb;
    const long k0 = (long)s * KCH + kg * 8;

    const unsigned short* ap[4];
    const unsigned short* bp[4];
    #pragma unroll
    for (int t = 0; t < 4; t++) {
        ap[t] = A + (long)(m0 + wm * 64 + t * 16 + lm) * 8192 + k0;
        bp[t] = Bw + (long)(n0 + wn * 64 + t * 16 + lm) * 8192 + k0;
    }

    f32x4 acc[4][4] = {};
    #pragma unroll 2
    for (int st = 0; st < NSTEP; ++st) {
        short8 Af[4], Bf[4];
        #pragma unroll
        for (int t = 0; t < 4; t++) {
            Af[t] = *(const short8*)(ap[t] + st * 32);
            Bf[t] = *(const short8*)(bp[t] + st * 32);
        }
        #pragma unroll
        for (int mt = 0; mt < 4; mt++)
            #pragma unroll
            for (int nt = 0; nt < 4; nt++)
                acc[mt][nt] = __builtin_amdgcn_mfma_f32_16x16x32_bf16(
                    Af[mt], Bf[nt], acc[mt][nt], 0, 0, 0);
    }

    #pragma unroll
    for (int mt = 0; mt < 4; mt++) {
        #pragma unroll
        for (int r = 0; r < 4; r++) {
            const int b = m0 + wm * 64 + mt * 16 + kg * 4 + r;
            #pragma unroll
            for (int nt = 0; nt < 4; nt++) {
                const int j = n0 + wn * 64 + nt * 16 + lm;
                parts[((long)s * 1024 + b) * 256 + j] = acc[mt][nt][r];
            }
        }
    }
}

// reduce split-K parts + alpha + bias + relu
template <int S>
__global__ void fc1_reduce(const float* __restrict__ parts,
                           const double* __restrict__ scr,
                           const float* __restrict__ bias,
                           float* __restrict__ f1) {
    const int idx = blockIdx.x * blockDim.x + threadIdx.x;  // < 262144
    const int j = idx & 255;
    float s = 0.f;
    #pragma unroll
    for (int p = 0; p < S; p++) s += parts[(long)p * 262144 + idx];
    const double c2 = scr[2];
    const float alpha = (float)(scr[1] / (c2 > 1.0 ? c2 : 1.0));
    f1[idx] = fmaxf(alpha * s + bias[j], 0.f);
}

__global__ void fc2_kernel(const float* __restrict__ a,
                           const float* __restrict__ wt,
                           const float* __restrict__ bias,
                           float* __restrict__ out, int B) {
    const int idx = blockIdx.x * blockDim.x + threadIdx.x;
    if (idx >= B * 10) return;
    const int k = idx % 10;
    const int b = idx / 10;
    const float* ar = a + (long)b * 256;
    const float* wr = wt + (long)k * 256;
    float acc = 0.f;
    #pragma unroll 4
    for (int i = 0; i < 256; i++) acc += ar[i] * wr[i];
    out[idx] = acc + bias[k];
}

extern "C" void kernel_launch(void* const* d_in, const int* in_sizes, int n_in,
                              void* d_out, int out_size, void* d_ws, size_t ws_size,
                              hipStream_t stream) {
    const float* x   = (const float*)d_in[0];
    const float* w1  = (const float*)d_in[1];
    const float* b1  = (const float*)d_in[2];
    const float* w2  = (const float*)d_in[3];
    const float* b2  = (const float*)d_in[4];
    const float* w3  = (const float*)d_in[5];
    const float* b3  = (const float*)d_in[6];
    const float* wf1 = (const float*)d_in[7];
    const float* bf1 = (const float*)d_in[8];
    const float* wf2 = (const float*)d_in[9];
    const float* bf2 = (const float*)d_in[10];
    float* out = (float*)d_out;
    float* ws = (float*)d_ws;

    const int B = 1024;

    float*    wt1   = ws + WS_WT1;
    unsigned* w2p   = (unsigned*)(ws + WS_W2P);
    unsigned* w3p   = (unsigned*)(ws + WS_W3P);
    unsigned* wtf1b = (unsigned*)(ws + WS_WTF1);
    float*    wtf2  = ws + WS_WTF2;
    unsigned* a1p   = (unsigned*)(ws + WS_A1);
    unsigned* a2p   = (unsigned*)(ws + WS_A2);
    unsigned* a3p   = (unsigned*)(ws + WS_A3);
    float*    f1    = ws + WS_F1;
    double*   scr   = (double*)(ws + WS_SCR);
    float*    parts = ws + WS_A1;      // alias: a1p dead after conv2

    hipMemsetAsync(scr, 0, 5 * 4 * sizeof(double), stream);

    TernArgs ta;
    ta.w[0] = w1;  ta.n[0] = N_WT1;
    ta.w[1] = w2;  ta.n[1] = 128 * 64 * 9;
    ta.w[2] = w3;  ta.n[2] = 256 * 128 * 9;
    ta.w[3] = wf1; ta.n[3] = 256 * 4096;
    ta.w[4] = wf2; ta.n[4] = 10 * 256;

    hipLaunchKernelGGL(tern_stats1, dim3(128, 5), dim3(256), 0, stream, ta, scr);
    hipLaunchKernelGGL(tern_stats2, dim3(128, 5), dim3(256), 0, stream, ta, scr);
    hipLaunchKernelGGL(tern_write_all, dim3(128, 5), dim3(256), 0, stream,
                       ta, scr, wt1, w2p, w3p, wtf1b, wtf2);

    // conv1: fp32 direct -> a1p (NHWC hi/lo)
    hipLaunchKernelGGL(conv1_kernel, dim3(B, 8), dim3(256), 0, stream,
                       x, wt1, b1, a1p);

    // conv2: CI2=128, HI=16, CO=128, HB=2 -> 2048 blocks
    hipLaunchKernelGGL((conv_mfma<128, 16, 128, 2>), dim3(B * 2), dim3(256), 0,
                       stream, a1p, (const unsigned short*)w2p, b2, scr + 4, a2p);

    // conv3: CI2=256, HI=8, CO=256, HB=1 -> 1024 blocks
    hipLaunchKernelGGL((conv_mfma<256, 8, 256, 1>), dim3(B), dim3(256), 0,
                       stream, a2p, (const unsigned short*)w3p, b3, scr + 8, a3p);

    // fc1: MFMA split-K + reduce(alpha+bias+relu)
    hipLaunchKernelGGL((fc1_mfma<FC1_S>), dim3(8, 2, FC1_S), dim3(256), 0, stream,
                       a3p, wtf1b, parts);
    hipLaunchKernelGGL((fc1_reduce<FC1_S>), dim3(1024), dim3(256), 0, stream,
                       parts, scr + 12, bf1, f1);

    // fc2
    hipLaunchKernelGGL(fc2_kernel, dim3((B * 10 + 255) / 256), dim3(256), 0,
                       stream, f1, wtf2, bf2, out, B);
}

// Round 5
// 402.783 us; speedup vs baseline: 37.1660x; 1.3799x over previous
//
#include <hip/hip_runtime.h>
#include <hip/hip_bf16.h>

// ---------------------------------------------------------------------------
// TernaryCIFAR10Net on MI355X — Round 5:
//   - convs: software-pipelined K-loop (2-stage reg double-buffer, no per-iter
//     barriers), chunk-major conflict-free LDS, plane-separated hi/lo
//     activations so the sign matrix B is stored once (K=CI), halving L2
//     weight traffic; each B-frag feeds hi+lo MFMAs.
//   - fc1 MFMA split-K with same register pipeline.
// Activation layout everywhere: per pixel row = [hi x C][lo x C] ushort(bf16).
// ---------------------------------------------------------------------------

typedef __attribute__((ext_vector_type(8))) short short8;
typedef __attribute__((ext_vector_type(4))) float f32x4;

__device__ __forceinline__ unsigned short f2bf(float x) {
    unsigned u = __float_as_uint(x);
    return (unsigned short)((u + 0x7fffu + ((u >> 16) & 1u)) >> 16);  // RNE
}
__device__ __forceinline__ float bf2f(unsigned short b) {
    return __uint_as_float(((unsigned)b) << 16);
}

// workspace layout (4-byte units)
#define WS_WT1   0
#define N_WT1    (64*3*3*3)
#define WS_W2P   (WS_WT1 + N_WT1)
#define N_W2P    (9*128*64)            // ushort signs [tap][co][ci] (half used)
#define WS_W3P   (WS_W2P + N_W2P)
#define N_W3P    (9*256*128)
#define WS_WTF1  (WS_W3P + N_W3P)
#define N_WTF1   (256*4096)            // ushort signs [256][8192]
#define WS_WTF2  (WS_WTF1 + N_WTF1)
#define N_WTF2   (10*256)
#define WS_A1    (WS_WTF2 + N_WTF2)
#define N_A1     (1024*256*64)         // a1: [B][256px][128 ushort]; fc1 parts alias
#define WS_A2    (WS_A1 + N_A1)
#define N_A2     (1024*64*128)         // a2: [B][64px][256 ushort]
#define WS_A3    (WS_A2 + N_A2)
#define N_A3     (1024*16*256)         // a3: [B][16px][512 ushort]
#define WS_F1    (WS_A3 + N_A3)
#define N_F1     (1024*256)
#define WS_SCR   (WS_F1 + N_F1)

#define FC1_S    16

struct TernArgs {
    const float* w[5];
    int n[5];
};

// ---------------------------------------------------------------------------
// Ternarize stats (fused over 5 weights): scr[wi] = {sum|w|, msum, count, pad}
// ---------------------------------------------------------------------------
__global__ void tern_stats1(TernArgs ta, double* __restrict__ scr) {
    const int wi = blockIdx.y;
    const float* __restrict__ w = ta.w[wi];
    const int n = ta.n[wi];
    double s = 0.0;
    for (int i = blockIdx.x * blockDim.x + threadIdx.x; i < n;
         i += gridDim.x * blockDim.x)
        s += (double)fabsf(w[i]);
    #pragma unroll
    for (int off = 32; off > 0; off >>= 1) s += __shfl_down(s, off, 64);
    __shared__ double red[4];
    const int lane = threadIdx.x & 63, wv = threadIdx.x >> 6;
    if (lane == 0) red[wv] = s;
    __syncthreads();
    if (threadIdx.x == 0)
        atomicAdd(scr + wi * 4, red[0] + red[1] + red[2] + red[3]);
}

__global__ void tern_stats2(TernArgs ta, double* __restrict__ scr) {
    const int wi = blockIdx.y;
    const float* __restrict__ w = ta.w[wi];
    const int n = ta.n[wi];
    const float delta = (float)(0.7 * scr[wi * 4] / (double)n);
    double ms = 0.0, cnt = 0.0;
    for (int i = blockIdx.x * blockDim.x + threadIdx.x; i < n;
         i += gridDim.x * blockDim.x) {
        float a = fabsf(w[i]);
        if (a > delta) { ms += (double)a; cnt += 1.0; }
    }
    #pragma unroll
    for (int off = 32; off > 0; off >>= 1) {
        ms += __shfl_down(ms, off, 64);
        cnt += __shfl_down(cnt, off, 64);
    }
    __shared__ double redm[4], redc[4];
    const int lane = threadIdx.x & 63, wv = threadIdx.x >> 6;
    if (lane == 0) { redm[wv] = ms; redc[wv] = cnt; }
    __syncthreads();
    if (threadIdx.x == 0) {
        atomicAdd(scr + wi * 4 + 1, redm[0] + redm[1] + redm[2] + redm[3]);
        atomicAdd(scr + wi * 4 + 2, redc[0] + redc[1] + redc[2] + redc[3]);
    }
}

// ---------------------------------------------------------------------------
// Fused writer.
//   0: w1  -> wt1 fp32 alpha*sign
//   1: w2  -> w2p ushort sign [tap][co][ci]   (CO=128, CI=64)
//   2: w3  -> w3p ushort sign                 (CO=256, CI=128)
//   3: wf1 -> wtf1b ushort sign [j][8192]: k = px*512 + c (hi), +256 (lo)
//   4: wf2 -> wtf2 fp32 alpha*sign
// ---------------------------------------------------------------------------
__global__ void tern_write_all(TernArgs ta, const double* __restrict__ scr,
                               float* __restrict__ wt1,
                               unsigned short* __restrict__ w2p,
                               unsigned short* __restrict__ w3p,
                               unsigned short* __restrict__ wtf1b,
                               float* __restrict__ wtf2) {
    const int wi = blockIdx.y;
    const float* __restrict__ w = ta.w[wi];
    const int n = ta.n[wi];
    const double* sc = scr + wi * 4;
    const float delta = (float)(0.7 * sc[0] / (double)n);
    const int i0 = blockIdx.x * blockDim.x + threadIdx.x;
    const int stride = gridDim.x * blockDim.x;

    if (wi == 0 || wi == 4) {
        const double c = sc[2];
        const float alpha = (float)(sc[1] / (c > 1.0 ? c : 1.0));
        float* dst = (wi == 0) ? wt1 : wtf2;
        for (int i = i0; i < n; i += stride) {
            float v = w[i];
            dst[i] = (fabsf(v) > delta) ? (v > 0.0f ? alpha : -alpha) : 0.0f;
        }
    } else if (wi == 1 || wi == 2) {
        const int CI = (wi == 1) ? 64 : 128;
        const int CO = (wi == 1) ? 128 : 256;
        unsigned short* dst = (wi == 1) ? w2p : w3p;
        for (int i = i0; i < n; i += stride) {
            const int co = i / (CI * 9);
            const int r = i % (CI * 9);
            const int ci = r / 9, tap = r % 9;
            float v = w[i];
            unsigned short s = (fabsf(v) > delta) ? (v > 0.0f ? 0x3f80 : 0xbf80) : 0;
            dst[(tap * CO + co) * CI + ci] = s;
        }
    } else {  // wi == 3: fc1 signs, hi and lo slots
        for (int i = i0; i < n; i += stride) {
            const int j = i >> 12;
            const int k = i & 4095;
            const int c = k >> 4, px = k & 15;
            float v = w[i];
            unsigned short s = (fabsf(v) > delta) ? (v > 0.0f ? 0x3f80 : 0xbf80) : 0;
            unsigned short* row = wtf1b + ((long)j << 13) + px * 512 + c;
            row[0] = s;          // hi slot
            row[256] = s;        // lo slot
        }
    }
}

// ---------------------------------------------------------------------------
// conv1: fp32 direct (CI=3), fused bias+relu+pool; output plane-split rows
// [hi 64][lo 64] ushort per pooled pixel.
// ---------------------------------------------------------------------------
__global__ __launch_bounds__(256) void conv1_kernel(
        const float* __restrict__ x, const float* __restrict__ wt,
        const float* __restrict__ bias, unsigned short* __restrict__ y) {
    constexpr int CI = 3, HI = 32, CO = 64, NCO = 8, PO = 16, NPX = 256;
    const int co0 = blockIdx.y * NCO;
    __shared__ float sw[NCO * CI * 12];
    for (int i = threadIdx.x; i < NCO * CI * 9; i += 256) {
        const int c = i / (CI * 9);
        const int r = i % (CI * 9);
        const int ci = r / 9, k = r % 9;
        sw[(c * CI + ci) * 12 + k] = wt[((long)(co0 + c) * CI + ci) * 9 + k];
    }
    __syncthreads();

    const int px = threadIdx.x;
    const int b = blockIdx.x;
    const int ph = px / PO, pw = px % PO;
    const int h0 = 2 * ph, w0 = 2 * pw;

    float acc[NCO][4];
    #pragma unroll
    for (int c = 0; c < NCO; c++)
        #pragma unroll
        for (int q = 0; q < 4; q++) acc[c][q] = 0.f;

    const float* xb = x + (long)b * CI * HI * HI;
    for (int ci = 0; ci < CI; ci++) {
        const float* xc = xb + ci * HI * HI;
        float p[4][4];
        #pragma unroll
        for (int r = 0; r < 4; r++) {
            const int h = h0 - 1 + r;
            const bool hin = (unsigned)h < (unsigned)HI;
            #pragma unroll
            for (int c2 = 0; c2 < 4; c2++) {
                const int w = w0 - 1 + c2;
                p[r][c2] = (hin && (unsigned)w < (unsigned)HI) ? xc[h * HI + w] : 0.f;
            }
        }
        #pragma unroll
        for (int c = 0; c < NCO; c++) {
            const float4* w4 = (const float4*)(sw + (c * CI + ci) * 12);
            const float4 wa = w4[0], wb = w4[1], wc = w4[2];
            const float wk[9] = {wa.x, wa.y, wa.z, wa.w, wb.x, wb.y, wb.z, wb.w, wc.x};
            #pragma unroll
            for (int kh = 0; kh < 3; kh++)
                #pragma unroll
                for (int kw = 0; kw < 3; kw++) {
                    const float wvv = wk[kh * 3 + kw];
                    acc[c][0] += wvv * p[kh][kw];
                    acc[c][1] += wvv * p[kh][kw + 1];
                    acc[c][2] += wvv * p[kh + 1][kw];
                    acc[c][3] += wvv * p[kh + 1][kw + 1];
                }
        }
    }
    unsigned short* yr = y + ((long)b * NPX + px) * (2 * CO);
    #pragma unroll
    for (int c = 0; c < NCO; c++) {
        float m = fmaxf(fmaxf(acc[c][0], acc[c][1]), fmaxf(acc[c][2], acc[c][3]));
        float o = fmaxf(m + bias[co0 + c], 0.f);
        unsigned short hi = f2bf(o);
        unsigned short lo = f2bf(o - bf2f(hi));
        yr[co0 + c] = hi;
        yr[CO + co0 + c] = lo;
    }
}

// ---------------------------------------------------------------------------
// MFMA conv, round-5 design.
//  - input rows [hi CI][lo CI]; LDS chunk-major: X[g][pixel][32] (g = plane*CH+ch)
//    -> conflict-free b128 reads/writes, no padding, cheap addressing.
//  - B = single signs [9][CO][CI]; one B-frag feeds hi- and lo-plane MFMAs.
//  - K-loop software-pipelined: regs double-buffered, loads for it+1 issued
//    before it's MFMAs; no barriers inside the loop.
//  - m-swizzle m=pp*4+sub keeps the 2x2 maxpool register-local.
// ---------------------------------------------------------------------------
template <int CI, int HI, int CO, int HB, int WN>
__global__ __launch_bounds__(256) void conv_mfma2(
        const unsigned short* __restrict__ xin,
        const unsigned short* __restrict__ wp,
        const float* __restrict__ bias,
        const double* __restrict__ scr,
        unsigned short* __restrict__ yout) {
    constexpr int CI2 = 2 * CI;
    constexpr int CH = CI / 32;
    constexpr int NITER = 9 * CH;
    constexpr int ROWS = HI / HB + 2;
    constexpr int COLS = HI + 2;
    constexpr int NPIX = ROWS * COLS;
    constexpr int PO = HI / 2;
    constexpr int POR = (HI / HB) / 2;
    constexpr int MT = 4, NT = 4;

    __shared__ unsigned short X[2 * CH * NPIX * 32];

    const int bimg = blockIdx.x / HB;
    const int hb = blockIdx.x % HB;
    const int tid = threadIdx.x;

    // zero fill (halo)
    constexpr int NZ = 2 * CH * NPIX * 4;   // int4 count
    for (int i = tid; i < NZ; i += 256) ((int4*)X)[i] = make_int4(0, 0, 0, 0);
    __syncthreads();

    // stage interior rows, chunk-major scatter
    constexpr int QPP = CI2 / 8;            // uint4 per pixel
    for (int i = tid; i < ROWS * HI * QPP; i += 256) {
        const int q = i % QPP;
        const int t = i / QPP;
        const int c = t % HI;
        const int r = t / HI;
        const int h = hb * (HI / HB) + r - 1;
        if ((unsigned)h < (unsigned)HI) {
            const uint4 v = *(const uint4*)(xin +
                ((long)(bimg * HI + h) * HI + c) * CI2 + q * 8);
            const int p = r * COLS + c + 1;
            *(uint4*)&X[(q >> 2) * (NPIX * 32) + p * 32 + (q & 3) * 8] = v;
        }
    }
    __syncthreads();

    const int lane = tid & 63;
    const int wid = tid >> 6;
    const int wm = wid / WN;
    const int wn = wid % WN;
    const int lm = lane & 15;
    const int kg = lane >> 4;
    const int kg8 = kg * 8;

    int pb[MT];
    #pragma unroll
    for (int mt = 0; mt < MT; mt++) {
        const int m = (wm * MT + mt) * 16 + lm;
        const int pp = m >> 2, sub = m & 3;
        const int lph = pp / PO, lpw = pp % PO;
        const int h = 2 * lph + (sub >> 1);
        const int w = 2 * lpw + (sub & 1);
        pb[mt] = h * COLS + w;              // padded coords, tap (0,0)
    }
    const unsigned short* bp[NT];
    #pragma unroll
    for (int nt = 0; nt < NT; nt++) {
        const int co = (wn * NT + nt) * 16 + lm;
        bp[nt] = wp + (long)co * CI + kg8;
    }

    f32x4 acc[MT][NT] = {};
    short8 Ab[2][MT][2], Bb[2][NT];

    // prologue: it = 0 (tap 0, ch 0)
    #pragma unroll
    for (int nt = 0; nt < NT; nt++) Bb[0][nt] = *(const short8*)(bp[nt]);
    #pragma unroll
    for (int mt = 0; mt < MT; mt++) {
        const int po = pb[mt] * 32 + kg8;
        Ab[0][mt][0] = *(const short8*)&X[po];
        Ab[0][mt][1] = *(const short8*)&X[CH * NPIX * 32 + po];
    }

    #pragma unroll 2
    for (int it = 0; it < NITER; ++it) {
        const int cur = it & 1, nxt = cur ^ 1;
        if (it + 1 < NITER) {
            const int it1 = it + 1;
            const int tap = it1 / CH, ch = it1 % CH;
            const int dtap = (tap / 3) * COLS + (tap % 3);
            const int woff = (tap * CO) * CI + ch * 32;
            #pragma unroll
            for (int nt = 0; nt < NT; nt++)
                Bb[nxt][nt] = *(const short8*)(bp[nt] + woff);
            const int g0 = ch * NPIX * 32;
            const int g1 = (CH + ch) * NPIX * 32;
            #pragma unroll
            for (int mt = 0; mt < MT; mt++) {
                const int po = (pb[mt] + dtap) * 32 + kg8;
                Ab[nxt][mt][0] = *(const short8*)&X[g0 + po];
                Ab[nxt][mt][1] = *(const short8*)&X[g1 + po];
            }
        }
        #pragma unroll
        for (int mt = 0; mt < MT; mt++)
            #pragma unroll
            for (int nt = 0; nt < NT; nt++) {
                acc[mt][nt] = __builtin_amdgcn_mfma_f32_16x16x32_bf16(
                    Ab[cur][mt][0], Bb[cur][nt], acc[mt][nt], 0, 0, 0);
                acc[mt][nt] = __builtin_amdgcn_mfma_f32_16x16x32_bf16(
                    Ab[cur][mt][1], Bb[cur][nt], acc[mt][nt], 0, 0, 0);
            }
    }

    // epilogue: lane's 4 C/D regs = the 2x2 pool members of pooled pixel pp
    const double c2 = scr[2];
    const float alpha = (float)(scr[1] / (c2 > 1.0 ? c2 : 1.0));
    #pragma unroll
    for (int mt = 0; mt < MT; mt++) {
        const int pp = (wm * MT + mt) * 4 + kg;
        const int lph = pp / PO, lpw = pp % PO;
        const int gpp = (hb * POR + lph) * PO + lpw;
        unsigned short* yr = yout + ((long)bimg * (PO * PO) + gpp) * (2 * CO);
        #pragma unroll
        for (int nt = 0; nt < NT; nt++) {
            const int co = (wn * NT + nt) * 16 + lm;
            const f32x4 a = acc[mt][nt];
            float v = fmaxf(fmaxf(a[0], a[1]), fmaxf(a[2], a[3]));
            float o = fmaxf(alpha * v + bias[co], 0.f);
            unsigned short hi = f2bf(o);
            unsigned short lo = f2bf(o - bf2f(hi));
            yr[co] = hi;
            yr[CO + co] = lo;
        }
    }
}

// ---------------------------------------------------------------------------
// fc1 MFMA: C[b][j] = sum_k A[b][k]*S[j][k], K=8192 (hi/lo slots), split-K,
// register-pipelined. parts[s][b][j] fp32.
// ---------------------------------------------------------------------------
template <int S>
__global__ __launch_bounds__(256) void fc1_mfma(
        const unsigned short* __restrict__ A,    // [1024][8192]
        const unsigned short* __restrict__ Bw,   // [256][8192]
        float* __restrict__ parts) {
    constexpr int KCH = 8192 / S;
    constexpr int NSTEP = KCH / 32;
    const int m0 = blockIdx.x * 128;
    const int n0 = blockIdx.y * 128;
    const int s = blockIdx.z;
    const int tid = threadIdx.x;
    const int lane = tid & 63, wid = tid >> 6;
    const int wm = wid >> 1, wn = wid & 1;
    const int lm = lane & 15, kg = lane >> 4;

    const long k0 = (long)s * KCH + kg * 8;
    const unsigned short* ap[4];
    const unsigned short* bp[4];
    #pragma unroll
    for (int t = 0; t < 4; t++) {
        ap[t] = A + (long)(m0 + wm * 64 + t * 16 + lm) * 8192 + k0;
        bp[t] = Bw + (long)(n0 + wn * 64 + t * 16 + lm) * 8192 + k0;
    }

    f32x4 acc[4][4] = {};
    short8 Ab[2][4], Bb[2][4];
    #pragma unroll
    for (int t = 0; t < 4; t++) {
        Ab[0][t] = *(const short8*)(ap[t]);
        Bb[0][t] = *(const short8*)(bp[t]);
    }

    #pragma unroll 2
    for (int st = 0; st < NSTEP; ++st) {
        const int cur = st & 1, nxt = cur ^ 1;
        if (st + 1 < NSTEP) {
            const int off = (st + 1) * 32;
            #pragma unroll
            for (int t = 0; t < 4; t++) {
                Ab[nxt][t] = *(const short8*)(ap[t] + off);
                Bb[nxt][t] = *(const short8*)(bp[t] + off);
            }
        }
        #pragma unroll
        for (int mt = 0; mt < 4; mt++)
            #pragma unroll
            for (int nt = 0; nt < 4; nt++)
                acc[mt][nt] = __builtin_amdgcn_mfma_f32_16x16x32_bf16(
                    Ab[cur][mt], Bb[cur][nt], acc[mt][nt], 0, 0, 0);
    }

    #pragma unroll
    for (int mt = 0; mt < 4; mt++) {
        #pragma unroll
        for (int r = 0; r < 4; r++) {
            const int b = m0 + wm * 64 + mt * 16 + kg * 4 + r;
            #pragma unroll
            for (int nt = 0; nt < 4; nt++) {
                const int j = n0 + wn * 64 + nt * 16 + lm;
                parts[((long)s * 1024 + b) * 256 + j] = acc[mt][nt][r];
            }
        }
    }
}

template <int S>
__global__ void fc1_reduce(const float* __restrict__ parts,
                           const double* __restrict__ scr,
                           const float* __restrict__ bias,
                           float* __restrict__ f1) {
    const int idx = blockIdx.x * blockDim.x + threadIdx.x;  // < 262144
    const int j = idx & 255;
    float s = 0.f;
    #pragma unroll
    for (int p = 0; p < S; p++) s += parts[(long)p * 262144 + idx];
    const double c2 = scr[2];
    const float alpha = (float)(scr[1] / (c2 > 1.0 ? c2 : 1.0));
    f1[idx] = fmaxf(alpha * s + bias[j], 0.f);
}

__global__ void fc2_kernel(const float* __restrict__ a,
                           const float* __restrict__ wt,
                           const float* __restrict__ bias,
                           float* __restrict__ out, int B) {
    const int idx = blockIdx.x * blockDim.x + threadIdx.x;
    if (idx >= B * 10) return;
    const int k = idx % 10;
    const int b = idx / 10;
    const float* ar = a + (long)b * 256;
    const float* wr = wt + (long)k * 256;
    float acc = 0.f;
    #pragma unroll 4
    for (int i = 0; i < 256; i++) acc += ar[i] * wr[i];
    out[idx] = acc + bias[k];
}

extern "C" void kernel_launch(void* const* d_in, const int* in_sizes, int n_in,
                              void* d_out, int out_size, void* d_ws, size_t ws_size,
                              hipStream_t stream) {
    const float* x   = (const float*)d_in[0];
    const float* w1  = (const float*)d_in[1];
    const float* b1  = (const float*)d_in[2];
    const float* w2  = (const float*)d_in[3];
    const float* b2  = (const float*)d_in[4];
    const float* w3  = (const float*)d_in[5];
    const float* b3  = (const float*)d_in[6];
    const float* wf1 = (const float*)d_in[7];
    const float* bf1 = (const float*)d_in[8];
    const float* wf2 = (const float*)d_in[9];
    const float* bf2 = (const float*)d_in[10];
    float* out = (float*)d_out;
    float* ws = (float*)d_ws;

    const int B = 1024;

    float*          wt1   = ws + WS_WT1;
    unsigned short* w2p   = (unsigned short*)(ws + WS_W2P);
    unsigned short* w3p   = (unsigned short*)(ws + WS_W3P);
    unsigned short* wtf1b = (unsigned short*)(ws + WS_WTF1);
    float*          wtf2  = ws + WS_WTF2;
    unsigned short* a1p   = (unsigned short*)(ws + WS_A1);
    unsigned short* a2p   = (unsigned short*)(ws + WS_A2);
    unsigned short* a3p   = (unsigned short*)(ws + WS_A3);
    float*          f1    = ws + WS_F1;
    double*         scr   = (double*)(ws + WS_SCR);
    float*          parts = ws + WS_A1;   // alias: a1 dead after conv2

    hipMemsetAsync(scr, 0, 5 * 4 * sizeof(double), stream);

    TernArgs ta;
    ta.w[0] = w1;  ta.n[0] = N_WT1;
    ta.w[1] = w2;  ta.n[1] = 128 * 64 * 9;
    ta.w[2] = w3;  ta.n[2] = 256 * 128 * 9;
    ta.w[3] = wf1; ta.n[3] = 256 * 4096;
    ta.w[4] = wf2; ta.n[4] = 10 * 256;

    hipLaunchKernelGGL(tern_stats1, dim3(128, 5), dim3(256), 0, stream, ta, scr);
    hipLaunchKernelGGL(tern_stats2, dim3(128, 5), dim3(256), 0, stream, ta, scr);
    hipLaunchKernelGGL(tern_write_all, dim3(128, 5), dim3(256), 0, stream,
                       ta, scr, wt1, w2p, w3p, wtf1b, wtf2);

    // conv1: fp32 direct -> a1 (plane-split rows)
    hipLaunchKernelGGL(conv1_kernel, dim3(B, 8), dim3(256), 0, stream,
                       x, wt1, b1, a1p);

    // conv2: CI=64, HI=16, CO=128, HB=2, WN=2 -> 2048 blocks
    hipLaunchKernelGGL((conv_mfma2<64, 16, 128, 2, 2>), dim3(B * 2), dim3(256),
                       0, stream, a1p, w2p, b2, scr + 4, a2p);

    // conv3: CI=128, HI=8, CO=256, HB=1, WN=4 -> 1024 blocks
    hipLaunchKernelGGL((conv_mfma2<128, 8, 256, 1, 4>), dim3(B), dim3(256),
                       0, stream, a2p, w3p, b3, scr + 8, a3p);

    // fc1: MFMA split-K + reduce(alpha+bias+relu)
    hipLaunchKernelGGL((fc1_mfma<FC1_S>), dim3(8, 2, FC1_S), dim3(256), 0, stream,
                       a3p, wtf1b, parts);
    hipLaunchKernelGGL((fc1_reduce<FC1_S>), dim3(1024), dim3(256), 0, stream,
                       parts, scr + 12, bf1, f1);

    // fc2
    hipLaunchKernelGGL(fc2_kernel, dim3((B * 10 + 255) / 256), dim3(256), 0,
                       stream, f1, wtf2, bf2, out, B);
}

// Round 6
// 399.814 us; speedup vs baseline: 37.4421x; 1.0074x over previous
//
#include <hip/hip_runtime.h>
#include <hip/hip_bf16.h>

// ---------------------------------------------------------------------------
// TernaryCIFAR10Net on MI355X — Round 6:
//   R5 + LDS bank-conflict elimination in conv_mfma2:
//     - slot swizzle (j + p/2)&3 for 16B sub-chunks within each pixel row
//       -> A-fragment ds_read_b128 conflict-free (was 8-way)
//     - plane stride padded +16 ushorts -> staging writes <=2-way
//     - halo-only LDS zeroing (was full-LDS zero pass)
// Activation layout everywhere: per pixel row = [hi x C][lo x C] ushort(bf16).
// ---------------------------------------------------------------------------

typedef __attribute__((ext_vector_type(8))) short short8;
typedef __attribute__((ext_vector_type(4))) float f32x4;

__device__ __forceinline__ unsigned short f2bf(float x) {
    unsigned u = __float_as_uint(x);
    return (unsigned short)((u + 0x7fffu + ((u >> 16) & 1u)) >> 16);  // RNE
}
__device__ __forceinline__ float bf2f(unsigned short b) {
    return __uint_as_float(((unsigned)b) << 16);
}

// workspace layout (4-byte units)
#define WS_WT1   0
#define N_WT1    (64*3*3*3)
#define WS_W2P   (WS_WT1 + N_WT1)
#define N_W2P    (9*128*64)
#define WS_W3P   (WS_W2P + N_W2P)
#define N_W3P    (9*256*128)
#define WS_WTF1  (WS_W3P + N_W3P)
#define N_WTF1   (256*4096)            // ushort signs [256][8192]
#define WS_WTF2  (WS_WTF1 + N_WTF1)
#define N_WTF2   (10*256)
#define WS_A1    (WS_WTF2 + N_WTF2)
#define N_A1     (1024*256*64)         // a1: [B][256px][128 ushort]; fc1 parts alias
#define WS_A2    (WS_A1 + N_A1)
#define N_A2     (1024*64*128)         // a2: [B][64px][256 ushort]
#define WS_A3    (WS_A2 + N_A2)
#define N_A3     (1024*16*256)         // a3: [B][16px][512 ushort]
#define WS_F1    (WS_A3 + N_A3)
#define N_F1     (1024*256)
#define WS_SCR   (WS_F1 + N_F1)

#define FC1_S    16

struct TernArgs {
    const float* w[5];
    int n[5];
};

// ---------------------------------------------------------------------------
// Ternarize stats (fused over 5 weights): scr[wi] = {sum|w|, msum, count, pad}
// ---------------------------------------------------------------------------
__global__ void tern_stats1(TernArgs ta, double* __restrict__ scr) {
    const int wi = blockIdx.y;
    const float* __restrict__ w = ta.w[wi];
    const int n = ta.n[wi];
    double s = 0.0;
    for (int i = blockIdx.x * blockDim.x + threadIdx.x; i < n;
         i += gridDim.x * blockDim.x)
        s += (double)fabsf(w[i]);
    #pragma unroll
    for (int off = 32; off > 0; off >>= 1) s += __shfl_down(s, off, 64);
    __shared__ double red[4];
    const int lane = threadIdx.x & 63, wv = threadIdx.x >> 6;
    if (lane == 0) red[wv] = s;
    __syncthreads();
    if (threadIdx.x == 0)
        atomicAdd(scr + wi * 4, red[0] + red[1] + red[2] + red[3]);
}

__global__ void tern_stats2(TernArgs ta, double* __restrict__ scr) {
    const int wi = blockIdx.y;
    const float* __restrict__ w = ta.w[wi];
    const int n = ta.n[wi];
    const float delta = (float)(0.7 * scr[wi * 4] / (double)n);
    double ms = 0.0, cnt = 0.0;
    for (int i = blockIdx.x * blockDim.x + threadIdx.x; i < n;
         i += gridDim.x * blockDim.x) {
        float a = fabsf(w[i]);
        if (a > delta) { ms += (double)a; cnt += 1.0; }
    }
    #pragma unroll
    for (int off = 32; off > 0; off >>= 1) {
        ms += __shfl_down(ms, off, 64);
        cnt += __shfl_down(cnt, off, 64);
    }
    __shared__ double redm[4], redc[4];
    const int lane = threadIdx.x & 63, wv = threadIdx.x >> 6;
    if (lane == 0) { redm[wv] = ms; redc[wv] = cnt; }
    __syncthreads();
    if (threadIdx.x == 0) {
        atomicAdd(scr + wi * 4 + 1, redm[0] + redm[1] + redm[2] + redm[3]);
        atomicAdd(scr + wi * 4 + 2, redc[0] + redc[1] + redc[2] + redc[3]);
    }
}

// ---------------------------------------------------------------------------
// Fused writer.
//   0: w1  -> wt1 fp32 alpha*sign
//   1: w2  -> w2p ushort sign [tap][co][ci]   (CO=128, CI=64)
//   2: w3  -> w3p ushort sign                 (CO=256, CI=128)
//   3: wf1 -> wtf1b ushort sign [j][8192]: k = px*512 + c (hi), +256 (lo)
//   4: wf2 -> wtf2 fp32 alpha*sign
// ---------------------------------------------------------------------------
__global__ void tern_write_all(TernArgs ta, const double* __restrict__ scr,
                               float* __restrict__ wt1,
                               unsigned short* __restrict__ w2p,
                               unsigned short* __restrict__ w3p,
                               unsigned short* __restrict__ wtf1b,
                               float* __restrict__ wtf2) {
    const int wi = blockIdx.y;
    const float* __restrict__ w = ta.w[wi];
    const int n = ta.n[wi];
    const double* sc = scr + wi * 4;
    const float delta = (float)(0.7 * sc[0] / (double)n);
    const int i0 = blockIdx.x * blockDim.x + threadIdx.x;
    const int stride = gridDim.x * blockDim.x;

    if (wi == 0 || wi == 4) {
        const double c = sc[2];
        const float alpha = (float)(sc[1] / (c > 1.0 ? c : 1.0));
        float* dst = (wi == 0) ? wt1 : wtf2;
        for (int i = i0; i < n; i += stride) {
            float v = w[i];
            dst[i] = (fabsf(v) > delta) ? (v > 0.0f ? alpha : -alpha) : 0.0f;
        }
    } else if (wi == 1 || wi == 2) {
        const int CI = (wi == 1) ? 64 : 128;
        const int CO = (wi == 1) ? 128 : 256;
        unsigned short* dst = (wi == 1) ? w2p : w3p;
        for (int i = i0; i < n; i += stride) {
            const int co = i / (CI * 9);
            const int r = i % (CI * 9);
            const int ci = r / 9, tap = r % 9;
            float v = w[i];
            unsigned short s = (fabsf(v) > delta) ? (v > 0.0f ? 0x3f80 : 0xbf80) : 0;
            dst[(tap * CO + co) * CI + ci] = s;
        }
    } else {  // wi == 3: fc1 signs, hi and lo slots
        for (int i = i0; i < n; i += stride) {
            const int j = i >> 12;
            const int k = i & 4095;
            const int c = k >> 4, px = k & 15;
            float v = w[i];
            unsigned short s = (fabsf(v) > delta) ? (v > 0.0f ? 0x3f80 : 0xbf80) : 0;
            unsigned short* row = wtf1b + ((long)j << 13) + px * 512 + c;
            row[0] = s;          // hi slot
            row[256] = s;        // lo slot
        }
    }
}

// ---------------------------------------------------------------------------
// conv1: fp32 direct (CI=3), fused bias+relu+pool; output plane-split rows
// [hi 64][lo 64] ushort per pooled pixel.
// ---------------------------------------------------------------------------
__global__ __launch_bounds__(256) void conv1_kernel(
        const float* __restrict__ x, const float* __restrict__ wt,
        const float* __restrict__ bias, unsigned short* __restrict__ y) {
    constexpr int CI = 3, HI = 32, CO = 64, NCO = 8, PO = 16, NPX = 256;
    const int co0 = blockIdx.y * NCO;
    __shared__ float sw[NCO * CI * 12];
    for (int i = threadIdx.x; i < NCO * CI * 9; i += 256) {
        const int c = i / (CI * 9);
        const int r = i % (CI * 9);
        const int ci = r / 9, k = r % 9;
        sw[(c * CI + ci) * 12 + k] = wt[((long)(co0 + c) * CI + ci) * 9 + k];
    }
    __syncthreads();

    const int px = threadIdx.x;
    const int b = blockIdx.x;
    const int ph = px / PO, pw = px % PO;
    const int h0 = 2 * ph, w0 = 2 * pw;

    float acc[NCO][4];
    #pragma unroll
    for (int c = 0; c < NCO; c++)
        #pragma unroll
        for (int q = 0; q < 4; q++) acc[c][q] = 0.f;

    const float* xb = x + (long)b * CI * HI * HI;
    for (int ci = 0; ci < CI; ci++) {
        const float* xc = xb + ci * HI * HI;
        float p[4][4];
        #pragma unroll
        for (int r = 0; r < 4; r++) {
            const int h = h0 - 1 + r;
            const bool hin = (unsigned)h < (unsigned)HI;
            #pragma unroll
            for (int c2 = 0; c2 < 4; c2++) {
                const int w = w0 - 1 + c2;
                p[r][c2] = (hin && (unsigned)w < (unsigned)HI) ? xc[h * HI + w] : 0.f;
            }
        }
        #pragma unroll
        for (int c = 0; c < NCO; c++) {
            const float4* w4 = (const float4*)(sw + (c * CI + ci) * 12);
            const float4 wa = w4[0], wb = w4[1], wc = w4[2];
            const float wk[9] = {wa.x, wa.y, wa.z, wa.w, wb.x, wb.y, wb.z, wb.w, wc.x};
            #pragma unroll
            for (int kh = 0; kh < 3; kh++)
                #pragma unroll
                for (int kw = 0; kw < 3; kw++) {
                    const float wvv = wk[kh * 3 + kw];
                    acc[c][0] += wvv * p[kh][kw];
                    acc[c][1] += wvv * p[kh][kw + 1];
                    acc[c][2] += wvv * p[kh + 1][kw];
                    acc[c][3] += wvv * p[kh + 1][kw + 1];
                }
        }
    }
    unsigned short* yr = y + ((long)b * NPX + px) * (2 * CO);
    #pragma unroll
    for (int c = 0; c < NCO; c++) {
        float m = fmaxf(fmaxf(acc[c][0], acc[c][1]), fmaxf(acc[c][2], acc[c][3]));
        float o = fmaxf(m + bias[co0 + c], 0.f);
        unsigned short hi = f2bf(o);
        unsigned short lo = f2bf(o - bf2f(hi));
        yr[co0 + c] = hi;
        yr[CO + co0 + c] = lo;
    }
}

// ---------------------------------------------------------------------------
// MFMA conv, round-6.
//  LDS layout: X[g][pixel][4 slots x 8ch], g = plane*CH + ch, plane stride
//  PSTR = NPIX*32+16 (plane bank offset 8 -> staging writes conflict-light).
//  Sub-chunk slot swizzle: logical sub-chunk j of pixel p lives at physical
//  slot (j + (p>>1)) & 3 -> A-fragment reads conflict-free (2-way max).
//  K-loop: 2-stage register pipeline, no per-iter barriers.
// ---------------------------------------------------------------------------
template <int CI, int HI, int CO, int HB, int WN>
__global__ __launch_bounds__(256) void conv_mfma2(
        const unsigned short* __restrict__ xin,
        const unsigned short* __restrict__ wp,
        const float* __restrict__ bias,
        const double* __restrict__ scr,
        unsigned short* __restrict__ yout) {
    constexpr int CI2 = 2 * CI;
    constexpr int CH = CI / 32;
    constexpr int NITER = 9 * CH;
    constexpr int ROWS = HI / HB + 2;
    constexpr int COLS = HI + 2;
    constexpr int NPIX = ROWS * COLS;
    constexpr int PSTR = NPIX * 32 + 16;    // plane stride, ushort units
    constexpr int PO = HI / 2;
    constexpr int POR = (HI / HB) / 2;
    constexpr int MT = 4, NT = 4;

    __shared__ unsigned short X[2 * CH * PSTR];

    const int bimg = blockIdx.x / HB;
    const int hb = blockIdx.x % HB;
    const int tid = threadIdx.x;

    // halo-only zero fill (borders; interior is fully overwritten below)
    constexpr int HALO = 2 * COLS + 2 * (ROWS - 2);
    {
        const int4 z = make_int4(0, 0, 0, 0);
        for (int i = tid; i < HALO * 2 * CH * 4; i += 256) {
            const int u = i & 3;
            const int t = i >> 2;
            const int g = t % (2 * CH);
            const int hp = t / (2 * CH);
            int p;
            if (hp < COLS) p = hp;
            else if (hp < 2 * COLS) p = (ROWS - 1) * COLS + (hp - COLS);
            else {
                const int e = hp - 2 * COLS;
                p = (1 + (e >> 1)) * COLS + ((e & 1) ? (COLS - 1) : 0);
            }
            ((int4*)&X[g * PSTR + p * 32])[u] = z;
        }
    }
    __syncthreads();

    // stage interior rows, chunk-major scatter with slot swizzle
    constexpr int QPP = CI2 / 8;            // uint4 per pixel
    for (int i = tid; i < ROWS * HI * QPP; i += 256) {
        const int q = i % QPP;
        const int t = i / QPP;
        const int c = t % HI;
        const int r = t / HI;
        const int h = hb * (HI / HB) + r - 1;
        if ((unsigned)h < (unsigned)HI) {
            const uint4 v = *(const uint4*)(xin +
                ((long)(bimg * HI + h) * HI + c) * CI2 + q * 8);
            const int p = r * COLS + c + 1;
            const int slot = ((q & 3) + (p >> 1)) & 3;
            *(uint4*)&X[(q >> 2) * PSTR + p * 32 + slot * 8] = v;
        }
    }
    __syncthreads();

    const int lane = tid & 63;
    const int wid = tid >> 6;
    const int wm = wid / WN;
    const int wn = wid % WN;
    const int lm = lane & 15;
    const int kg = lane >> 4;

    int pb[MT];
    #pragma unroll
    for (int mt = 0; mt < MT; mt++) {
        const int m = (wm * MT + mt) * 16 + lm;
        const int pp = m >> 2, sub = m & 3;
        const int lph = pp / PO, lpw = pp % PO;
        const int h = 2 * lph + (sub >> 1);
        const int w = 2 * lpw + (sub & 1);
        pb[mt] = h * COLS + w;              // padded coords, tap (0,0)
    }
    const unsigned short* bp[NT];
    #pragma unroll
    for (int nt = 0; nt < NT; nt++) {
        const int co = (wn * NT + nt) * 16 + lm;
        bp[nt] = wp + (long)co * CI + kg * 8;
    }

    f32x4 acc[MT][NT] = {};
    short8 Ab[2][MT][2], Bb[2][NT];

    // prologue: it = 0 (tap 0, ch 0)
    #pragma unroll
    for (int nt = 0; nt < NT; nt++) Bb[0][nt] = *(const short8*)(bp[nt]);
    #pragma unroll
    for (int mt = 0; mt < MT; mt++) {
        const int p = pb[mt];
        const int ao = p * 32 + (((kg + (p >> 1)) & 3) << 3);
        Ab[0][mt][0] = *(const short8*)&X[ao];
        Ab[0][mt][1] = *(const short8*)&X[CH * PSTR + ao];
    }

    #pragma unroll 2
    for (int it = 0; it < NITER; ++it) {
        const int cur = it & 1, nxt = cur ^ 1;
        if (it + 1 < NITER) {
            const int it1 = it + 1;
            const int tap = it1 / CH, ch = it1 % CH;
            const int dtap = (tap / 3) * COLS + (tap % 3);
            const int woff = (tap * CO) * CI + ch * 32;
            #pragma unroll
            for (int nt = 0; nt < NT; nt++)
                Bb[nxt][nt] = *(const short8*)(bp[nt] + woff);
            #pragma unroll
            for (int mt = 0; mt < MT; mt++) {
                const int p = pb[mt] + dtap;
                const int ao = p * 32 + (((kg + (p >> 1)) & 3) << 3);
                Ab[nxt][mt][0] = *(const short8*)&X[ch * PSTR + ao];
                Ab[nxt][mt][1] = *(const short8*)&X[(CH + ch) * PSTR + ao];
            }
        }
        #pragma unroll
        for (int mt = 0; mt < MT; mt++)
            #pragma unroll
            for (int nt = 0; nt < NT; nt++) {
                acc[mt][nt] = __builtin_amdgcn_mfma_f32_16x16x32_bf16(
                    Ab[cur][mt][0], Bb[cur][nt], acc[mt][nt], 0, 0, 0);
                acc[mt][nt] = __builtin_amdgcn_mfma_f32_16x16x32_bf16(
                    Ab[cur][mt][1], Bb[cur][nt], acc[mt][nt], 0, 0, 0);
            }
    }

    // epilogue: lane's 4 C/D regs = the 2x2 pool members of pooled pixel pp
    const double c2 = scr[2];
    const float alpha = (float)(scr[1] / (c2 > 1.0 ? c2 : 1.0));
    #pragma unroll
    for (int mt = 0; mt < MT; mt++) {
        const int pp = (wm * MT + mt) * 4 + kg;
        const int lph = pp / PO, lpw = pp % PO;
        const int gpp = (hb * POR + lph) * PO + lpw;
        unsigned short* yr = yout + ((long)bimg * (PO * PO) + gpp) * (2 * CO);
        #pragma unroll
        for (int nt = 0; nt < NT; nt++) {
            const int co = (wn * NT + nt) * 16 + lm;
            const f32x4 a = acc[mt][nt];
            float v = fmaxf(fmaxf(a[0], a[1]), fmaxf(a[2], a[3]));
            float o = fmaxf(alpha * v + bias[co], 0.f);
            unsigned short hi = f2bf(o);
            unsigned short lo = f2bf(o - bf2f(hi));
            yr[co] = hi;
            yr[CO + co] = lo;
        }
    }
}

// ---------------------------------------------------------------------------
// fc1 MFMA: C[b][j] = sum_k A[b][k]*S[j][k], K=8192 (hi/lo slots), split-K,
// register-pipelined. parts[s][b][j] fp32.
// ---------------------------------------------------------------------------
template <int S>
__global__ __launch_bounds__(256) void fc1_mfma(
        const unsigned short* __restrict__ A,    // [1024][8192]
        const unsigned short* __restrict__ Bw,   // [256][8192]
        float* __restrict__ parts) {
    constexpr int KCH = 8192 / S;
    constexpr int NSTEP = KCH / 32;
    const int m0 = blockIdx.x * 128;
    const int n0 = blockIdx.y * 128;
    const int s = blockIdx.z;
    const int tid = threadIdx.x;
    const int lane = tid & 63, wid = tid >> 6;
    const int wm = wid >> 1, wn = wid & 1;
    const int lm = lane & 15, kg = lane >> 4;

    const long k0 = (long)s * KCH + kg * 8;
    const unsigned short* ap[4];
    const unsigned short* bp[4];
    #pragma unroll
    for (int t = 0; t < 4; t++) {
        ap[t] = A + (long)(m0 + wm * 64 + t * 16 + lm) * 8192 + k0;
        bp[t] = Bw + (long)(n0 + wn * 64 + t * 16 + lm) * 8192 + k0;
    }

    f32x4 acc[4][4] = {};
    short8 Ab[2][4], Bb[2][4];
    #pragma unroll
    for (int t = 0; t < 4; t++) {
        Ab[0][t] = *(const short8*)(ap[t]);
        Bb[0][t] = *(const short8*)(bp[t]);
    }

    #pragma unroll 2
    for (int st = 0; st < NSTEP; ++st) {
        const int cur = st & 1, nxt = cur ^ 1;
        if (st + 1 < NSTEP) {
            const int off = (st + 1) * 32;
            #pragma unroll
            for (int t = 0; t < 4; t++) {
                Ab[nxt][t] = *(const short8*)(ap[t] + off);
                Bb[nxt][t] = *(const short8*)(bp[t] + off);
            }
        }
        #pragma unroll
        for (int mt = 0; mt < 4; mt++)
            #pragma unroll
            for (int nt = 0; nt < 4; nt++)
                acc[mt][nt] = __builtin_amdgcn_mfma_f32_16x16x32_bf16(
                    Ab[cur][mt], Bb[cur][nt], acc[mt][nt], 0, 0, 0);
    }

    #pragma unroll
    for (int mt = 0; mt < 4; mt++) {
        #pragma unroll
        for (int r = 0; r < 4; r++) {
            const int b = m0 + wm * 64 + mt * 16 + kg * 4 + r;
            #pragma unroll
            for (int nt = 0; nt < 4; nt++) {
                const int j = n0 + wn * 64 + nt * 16 + lm;
                parts[((long)s * 1024 + b) * 256 + j] = acc[mt][nt][r];
            }
        }
    }
}

template <int S>
__global__ void fc1_reduce(const float* __restrict__ parts,
                           const double* __restrict__ scr,
                           const float* __restrict__ bias,
                           float* __restrict__ f1) {
    const int idx = blockIdx.x * blockDim.x + threadIdx.x;  // < 262144
    const int j = idx & 255;
    float s = 0.f;
    #pragma unroll
    for (int p = 0; p < S; p++) s += parts[(long)p * 262144 + idx];
    const double c2 = scr[2];
    const float alpha = (float)(scr[1] / (c2 > 1.0 ? c2 : 1.0));
    f1[idx] = fmaxf(alpha * s + bias[j], 0.f);
}

__global__ void fc2_kernel(const float* __restrict__ a,
                           const float* __restrict__ wt,
                           const float* __restrict__ bias,
                           float* __restrict__ out, int B) {
    const int idx = blockIdx.x * blockDim.x + threadIdx.x;
    if (idx >= B * 10) return;
    const int k = idx % 10;
    const int b = idx / 10;
    const float* ar = a + (long)b * 256;
    const float* wr = wt + (long)k * 256;
    float acc = 0.f;
    #pragma unroll 4
    for (int i = 0; i < 256; i++) acc += ar[i] * wr[i];
    out[idx] = acc + bias[k];
}

extern "C" void kernel_launch(void* const* d_in, const int* in_sizes, int n_in,
                              void* d_out, int out_size, void* d_ws, size_t ws_size,
                              hipStream_t stream) {
    const float* x   = (const float*)d_in[0];
    const float* w1  = (const float*)d_in[1];
    const float* b1  = (const float*)d_in[2];
    const float* w2  = (const float*)d_in[3];
    const float* b2  = (const float*)d_in[4];
    const float* w3  = (const float*)d_in[5];
    const float* b3  = (const float*)d_in[6];
    const float* wf1 = (const float*)d_in[7];
    const float* bf1 = (const float*)d_in[8];
    const float* wf2 = (const float*)d_in[9];
    const float* bf2 = (const float*)d_in[10];
    float* out = (float*)d_out;
    float* ws = (float*)d_ws;

    const int B = 1024;

    float*          wt1   = ws + WS_WT1;
    unsigned short* w2p   = (unsigned short*)(ws + WS_W2P);
    unsigned short* w3p   = (unsigned short*)(ws + WS_W3P);
    unsigned short* wtf1b = (unsigned short*)(ws + WS_WTF1);
    float*          wtf2  = ws + WS_WTF2;
    unsigned short* a1p   = (unsigned short*)(ws + WS_A1);
    unsigned short* a2p   = (unsigned short*)(ws + WS_A2);
    unsigned short* a3p   = (unsigned short*)(ws + WS_A3);
    float*          f1    = ws + WS_F1;
    double*         scr   = (double*)(ws + WS_SCR);
    float*          parts = ws + WS_A1;   // alias: a1 dead after conv2

    hipMemsetAsync(scr, 0, 5 * 4 * sizeof(double), stream);

    TernArgs ta;
    ta.w[0] = w1;  ta.n[0] = N_WT1;
    ta.w[1] = w2;  ta.n[1] = 128 * 64 * 9;
    ta.w[2] = w3;  ta.n[2] = 256 * 128 * 9;
    ta.w[3] = wf1; ta.n[3] = 256 * 4096;
    ta.w[4] = wf2; ta.n[4] = 10 * 256;

    hipLaunchKernelGGL(tern_stats1, dim3(128, 5), dim3(256), 0, stream, ta, scr);
    hipLaunchKernelGGL(tern_stats2, dim3(128, 5), dim3(256), 0, stream, ta, scr);
    hipLaunchKernelGGL(tern_write_all, dim3(128, 5), dim3(256), 0, stream,
                       ta, scr, wt1, w2p, w3p, wtf1b, wtf2);

    // conv1: fp32 direct -> a1 (plane-split rows)
    hipLaunchKernelGGL(conv1_kernel, dim3(B, 8), dim3(256), 0, stream,
                       x, wt1, b1, a1p);

    // conv2: CI=64, HI=16, CO=128, HB=2, WN=2 -> 2048 blocks
    hipLaunchKernelGGL((conv_mfma2<64, 16, 128, 2, 2>), dim3(B * 2), dim3(256),
                       0, stream, a1p, w2p, b2, scr + 4, a2p);

    // conv3: CI=128, HI=8, CO=256, HB=1, WN=4 -> 1024 blocks
    hipLaunchKernelGGL((conv_mfma2<128, 8, 256, 1, 4>), dim3(B), dim3(256),
                       0, stream, a2p, w3p, b3, scr + 8, a3p);

    // fc1: MFMA split-K + reduce(alpha+bias+relu)
    hipLaunchKernelGGL((fc1_mfma<FC1_S>), dim3(8, 2, FC1_S), dim3(256), 0, stream,
                       a3p, wtf1b, parts);
    hipLaunchKernelGGL((fc1_reduce<FC1_S>), dim3(1024), dim3(256), 0, stream,
                       parts, scr + 12, bf1, f1);

    // fc2
    hipLaunchKernelGGL(fc2_kernel, dim3((B * 10 + 255) / 256), dim3(256), 0,
                       stream, f1, wtf2, bf2, out, B);
}